// Round 1
// baseline (842.140 us; speedup 1.0000x reference)
//
#include <hip/hip_runtime.h>
#include <cmath>

// GATv2 3-layer forward. Strategy:
//  - Build CSR over dst (counting sort) once per call; self-loop stored at slot 0.
//  - Per layer: dual-output fp32 tiled GEMM (xl = x@Wl, xr = x@Wr), then a
//    node-centric fused kernel: 1 wave per node, online softmax over incoming
//    edges, xl[src] gathered once per edge, bias+activation fused.
//  - No float atomics anywhere; only int atomics in CSR build.

#define NFEAT 128
#define HID 256
#define NCLS 47

__device__ __forceinline__ float group8_sum(float v) {
  v += __shfl_xor(v, 1, 64);
  v += __shfl_xor(v, 2, 64);
  v += __shfl_xor(v, 4, 64);
  return v;
}

// ---------------- CSR build ----------------
__global__ void k_init_deg(int* __restrict__ deg, int n) {
  int i = blockIdx.x * blockDim.x + threadIdx.x;
  if (i < n) deg[i] = 1;  // implicit self-loop
}

__global__ void k_count(const int* __restrict__ dst, int* __restrict__ deg, int e) {
  int i = blockIdx.x * blockDim.x + threadIdx.x;
  if (i < e) atomicAdd(&deg[dst[i]], 1);
}

__global__ __launch_bounds__(1024) void k_scan(const int* __restrict__ deg,
                                               int* __restrict__ rowptr, int n) {
  __shared__ int sdata[1024];
  __shared__ int s_carry;
  int t = threadIdx.x;
  if (t == 0) { s_carry = 0; rowptr[0] = 0; }
  __syncthreads();
  for (int base = 0; base < n; base += 1024) {
    int i = base + t;
    int v = (i < n) ? deg[i] : 0;
    sdata[t] = v;
    __syncthreads();
    for (int off = 1; off < 1024; off <<= 1) {
      int add = (t >= off) ? sdata[t - off] : 0;
      __syncthreads();
      sdata[t] += add;
      __syncthreads();
    }
    int inc = sdata[t] + s_carry;
    if (i < n) rowptr[i + 1] = inc;
    __syncthreads();
    if (t == 1023) s_carry = inc;
    __syncthreads();
  }
}

__global__ void k_init_csr(const int* __restrict__ rowptr, int* __restrict__ adj,
                           int* __restrict__ cursor, int n) {
  int i = blockIdx.x * blockDim.x + threadIdx.x;
  if (i < n) { int p = rowptr[i]; adj[p] = i; cursor[i] = p + 1; }
}

__global__ void k_scatter(const int* __restrict__ src, const int* __restrict__ dst,
                          int* __restrict__ cursor, int* __restrict__ adj, int e) {
  int i = blockIdx.x * blockDim.x + threadIdx.x;
  if (i < e) { int p = atomicAdd(&cursor[dst[i]], 1); adj[p] = src[i]; }
}

// ---------------- dual GEMM: XL = X@Wl, XR = X@Wr ----------------
// X: [N,K] row-major, Wl/Wr: [K,M] row-major. 64x64 tile, BK=16, 256 threads,
// 4x4 register blocking per output matrix.
__global__ __launch_bounds__(256) void gemm_dual(
    const float* __restrict__ X, const float* __restrict__ Wl,
    const float* __restrict__ Wr, float* __restrict__ XL, float* __restrict__ XR,
    int N, int K, int M) {
  __shared__ float Xs[64][17];  // +1 pad: avoids 16-way bank conflict on column reads
  __shared__ float Wls[16][64];
  __shared__ float Wrs[16][64];

  const int t = threadIdx.x;
  const int row0 = blockIdx.x * 64;
  const int col0 = blockIdx.y * 64;
  const int tx = t & 15, ty = t >> 4;
  const int lr = t >> 2;          // X-tile row this thread loads
  const int lk = (t & 3) * 4;     // X-tile k-offset
  const int wk = t >> 4;          // W-tile k-row
  const int wc = (t & 15) * 4;    // W-tile col-offset
  const bool mvec = ((M & 3) == 0);

  float accL[4][4] = {{0}}, accR[4][4] = {{0}};

  for (int k0 = 0; k0 < K; k0 += 16) {
    int grow = row0 + lr;
    if (grow < N) {
      const float4 xv = *reinterpret_cast<const float4*>(X + (size_t)grow * K + k0 + lk);
      Xs[lr][lk + 0] = xv.x; Xs[lr][lk + 1] = xv.y;
      Xs[lr][lk + 2] = xv.z; Xs[lr][lk + 3] = xv.w;
    } else {
      Xs[lr][lk + 0] = 0.f; Xs[lr][lk + 1] = 0.f;
      Xs[lr][lk + 2] = 0.f; Xs[lr][lk + 3] = 0.f;
    }
    if (mvec) {
      *reinterpret_cast<float4*>(&Wls[wk][wc]) =
          *reinterpret_cast<const float4*>(Wl + (size_t)(k0 + wk) * M + col0 + wc);
      *reinterpret_cast<float4*>(&Wrs[wk][wc]) =
          *reinterpret_cast<const float4*>(Wr + (size_t)(k0 + wk) * M + col0 + wc);
    } else {
      #pragma unroll
      for (int j = 0; j < 4; ++j) {
        int c = col0 + wc + j;
        Wls[wk][wc + j] = (c < M) ? Wl[(size_t)(k0 + wk) * M + c] : 0.f;
        Wrs[wk][wc + j] = (c < M) ? Wr[(size_t)(k0 + wk) * M + c] : 0.f;
      }
    }
    __syncthreads();
    #pragma unroll
    for (int kk = 0; kk < 16; ++kk) {
      float xs[4];
      #pragma unroll
      for (int i = 0; i < 4; ++i) xs[i] = Xs[ty * 4 + i][kk];
      const float4 wl = *reinterpret_cast<const float4*>(&Wls[kk][tx * 4]);
      const float4 wr = *reinterpret_cast<const float4*>(&Wrs[kk][tx * 4]);
      #pragma unroll
      for (int i = 0; i < 4; ++i) {
        accL[i][0] += xs[i] * wl.x; accL[i][1] += xs[i] * wl.y;
        accL[i][2] += xs[i] * wl.z; accL[i][3] += xs[i] * wl.w;
        accR[i][0] += xs[i] * wr.x; accR[i][1] += xs[i] * wr.y;
        accR[i][2] += xs[i] * wr.z; accR[i][3] += xs[i] * wr.w;
      }
    }
    __syncthreads();
  }

  #pragma unroll
  for (int i = 0; i < 4; ++i) {
    int r = row0 + ty * 4 + i;
    if (r >= N) continue;
    int cbase = col0 + tx * 4;
    if (mvec && cbase + 3 < M) {
      *reinterpret_cast<float4*>(XL + (size_t)r * M + cbase) =
          make_float4(accL[i][0], accL[i][1], accL[i][2], accL[i][3]);
      *reinterpret_cast<float4*>(XR + (size_t)r * M + cbase) =
          make_float4(accR[i][0], accR[i][1], accR[i][2], accR[i][3]);
    } else {
      #pragma unroll
      for (int j = 0; j < 4; ++j) {
        int c = cbase + j;
        if (c < M) {
          XL[(size_t)r * M + c] = accL[i][j];
          XR[(size_t)r * M + c] = accR[i][j];
        }
      }
    }
  }
}

// ---------------- fused node kernel, layers 0/1 (H=8, C=32) ----------------
// One wave per node. lane holds elements [4*lane, 4*lane+4) of the 256-vector;
// head h = lane>>3. Online softmax over incoming edges; ELU+bias epilogue.
__global__ __launch_bounds__(256) void gat_node_hc(
    const float* __restrict__ xl, const float* __restrict__ xr,
    const float* __restrict__ att, const float* __restrict__ bias,
    const int* __restrict__ rowptr, const int* __restrict__ adj,
    float* __restrict__ out, int n) {
  int wid = (blockIdx.x * blockDim.x + threadIdx.x) >> 6;
  int lane = threadIdx.x & 63;
  if (wid >= n) return;

  const float4 xrv = *reinterpret_cast<const float4*>(xr + (size_t)wid * HID + lane * 4);
  const float4 a = *reinterpret_cast<const float4*>(att + lane * 4);

  float m = -INFINITY, denom = 0.f;
  float4 acc = make_float4(0.f, 0.f, 0.f, 0.f);

  const int beg = rowptr[wid], end = rowptr[wid + 1];
  int u = adj[beg];
  for (int i = beg; i < end; ++i) {
    int unext = (i + 1 < end) ? adj[i + 1] : u;  // prefetch next src id
    const float4 xlu = *reinterpret_cast<const float4*>(xl + (size_t)u * HID + lane * 4);
    float ex = xlu.x + xrv.x; ex = ex > 0.f ? ex : 0.2f * ex;
    float ey = xlu.y + xrv.y; ey = ey > 0.f ? ey : 0.2f * ey;
    float ez = xlu.z + xrv.z; ez = ez > 0.f ? ez : 0.2f * ez;
    float ew = xlu.w + xrv.w; ew = ew > 0.f ? ew : 0.2f * ew;
    float part = ex * a.x + ey * a.y + ez * a.z + ew * a.w;
    part = group8_sum(part);  // logit for this edge's head h = lane>>3
    float mn = fmaxf(m, part);
    float so = __expf(m - mn);       // rescale old state (0 when m=-inf)
    float wn = __expf(part - mn);
    denom = denom * so + wn;
    acc.x = acc.x * so + wn * xlu.x;
    acc.y = acc.y * so + wn * xlu.y;
    acc.z = acc.z * so + wn * xlu.z;
    acc.w = acc.w * so + wn * xlu.w;
    m = mn;
    u = unext;
  }

  const float inv = 1.f / (denom + 1e-16f);
  const float4 bv = *reinterpret_cast<const float4*>(bias + lane * 4);
  float o[4] = {acc.x * inv + bv.x, acc.y * inv + bv.y,
                acc.z * inv + bv.z, acc.w * inv + bv.w};
  #pragma unroll
  for (int j = 0; j < 4; ++j) o[j] = o[j] > 0.f ? o[j] : (__expf(o[j]) - 1.f);  // ELU
  *reinterpret_cast<float4*>(out + (size_t)wid * HID + lane * 4) =
      make_float4(o[0], o[1], o[2], o[3]);
}

// ---------------- fused node kernel, layer 2 (H=1, C=47) + log_softmax ----------------
__global__ __launch_bounds__(256) void gat_node_l2(
    const float* __restrict__ xl, const float* __restrict__ xr,
    const float* __restrict__ att, const float* __restrict__ bias,
    const int* __restrict__ rowptr, const int* __restrict__ adj,
    float* __restrict__ out, int n) {
  int wid = (blockIdx.x * blockDim.x + threadIdx.x) >> 6;
  int lane = threadIdx.x & 63;
  if (wid >= n) return;
  const bool act = lane < NCLS;

  const float xrv = act ? xr[(size_t)wid * NCLS + lane] : 0.f;
  const float a = act ? att[lane] : 0.f;

  float m = -INFINITY, denom = 0.f, acc = 0.f;
  const int beg = rowptr[wid], end = rowptr[wid + 1];
  int u = adj[beg];
  for (int i = beg; i < end; ++i) {
    int unext = (i + 1 < end) ? adj[i + 1] : u;
    float xlu = act ? xl[(size_t)u * NCLS + lane] : 0.f;
    float e = xlu + xrv; e = e > 0.f ? e : 0.2f * e;
    float part = e * a;
    #pragma unroll
    for (int off = 1; off < 64; off <<= 1) part += __shfl_xor(part, off, 64);
    float mn = fmaxf(m, part);
    float so = __expf(m - mn);
    float wn = __expf(part - mn);
    denom = denom * so + wn;
    acc = acc * so + wn * xlu;
    m = mn;
    u = unext;
  }

  float r = acc / (denom + 1e-16f) + (act ? bias[lane] : 0.f);
  // log_softmax across the 47 classes (held one-per-lane)
  float rm = act ? r : -INFINITY;
  #pragma unroll
  for (int off = 1; off < 64; off <<= 1) rm = fmaxf(rm, __shfl_xor(rm, off, 64));
  float se = act ? __expf(r - rm) : 0.f;
  #pragma unroll
  for (int off = 1; off < 64; off <<= 1) se += __shfl_xor(se, off, 64);
  if (act) out[(size_t)wid * NCLS + lane] = r - rm - __logf(se);
}

// ---------------- launch ----------------
extern "C" void kernel_launch(void* const* d_in, const int* in_sizes, int n_in,
                              void* d_out, int out_size, void* d_ws, size_t ws_size,
                              hipStream_t stream) {
  const float* x  = (const float*)d_in[0];
  const int* ei   = (const int*)d_in[1];
  const float* Wl0 = (const float*)d_in[2];
  const float* Wr0 = (const float*)d_in[3];
  const float* a0  = (const float*)d_in[4];
  const float* b0  = (const float*)d_in[5];
  const float* Wl1 = (const float*)d_in[6];
  const float* Wr1 = (const float*)d_in[7];
  const float* a1  = (const float*)d_in[8];
  const float* b1  = (const float*)d_in[9];
  const float* Wl2 = (const float*)d_in[10];
  const float* Wr2 = (const float*)d_in[11];
  const float* a2  = (const float*)d_in[12];
  const float* b2  = (const float*)d_in[13];

  const int N = in_sizes[0] / NFEAT;   // 50000
  const int E = in_sizes[1] / 2;       // 800000
  const int* src = ei;
  const int* dst = ei + E;

  // workspace carve-up (~158 MB)
  char* ws = (char*)d_ws;
  float* xl = (float*)ws;  ws += (size_t)N * HID * sizeof(float);
  float* xr = (float*)ws;  ws += (size_t)N * HID * sizeof(float);
  float* hA = (float*)ws;  ws += (size_t)N * HID * sizeof(float);
  int* deg    = (int*)ws;  ws += (size_t)N * sizeof(int);        // reused as cursor
  int* rowptr = (int*)ws;  ws += (size_t)(N + 1) * sizeof(int);
  int* adj    = (int*)ws;  ws += (size_t)(E + N) * sizeof(int);

  const int TB = 256;
  // --- CSR build (per call; reused by all 3 layers) ---
  k_init_deg<<<(N + TB - 1) / TB, TB, 0, stream>>>(deg, N);
  k_count<<<(E + TB - 1) / TB, TB, 0, stream>>>(dst, deg, E);
  k_scan<<<1, 1024, 0, stream>>>(deg, rowptr, N);
  k_init_csr<<<(N + TB - 1) / TB, TB, 0, stream>>>(rowptr, adj, deg, N);
  k_scatter<<<(E + TB - 1) / TB, TB, 0, stream>>>(src, dst, deg, adj, E);

  const int nodeBlocks = (N + 3) / 4;  // 4 waves per block, 1 wave per node

  // --- layer 0 ---
  {
    dim3 g((N + 63) / 64, HID / 64);
    gemm_dual<<<g, 256, 0, stream>>>(x, Wl0, Wr0, xl, xr, N, NFEAT, HID);
    gat_node_hc<<<nodeBlocks, 256, 0, stream>>>(xl, xr, a0, b0, rowptr, adj, hA, N);
  }
  // --- layer 1 ---
  {
    dim3 g((N + 63) / 64, HID / 64);
    gemm_dual<<<g, 256, 0, stream>>>(hA, Wl1, Wr1, xl, xr, N, HID, HID);
    gat_node_hc<<<nodeBlocks, 256, 0, stream>>>(xl, xr, a1, b1, rowptr, adj, hA, N);
  }
  // --- layer 2 (output + log_softmax) ---
  {
    dim3 g((N + 63) / 64, 1);
    gemm_dual<<<g, 256, 0, stream>>>(hA, Wl2, Wr2, xl, xr, N, HID, NCLS);
    gat_node_l2<<<nodeBlocks, 256, 0, stream>>>(xl, xr, a2, b2, rowptr, adj,
                                                (float*)d_out, N);
  }
}

// Round 2
// 619.090 us; speedup vs baseline: 1.3603x; 1.3603x over previous
//
#include <hip/hip_runtime.h>
#include <cmath>

// GATv2 3-layer forward, round 1: bf16-MFMA GEMMs.
//  - CSR over dst (counting sort) once per call; self-loop at slot 0.
//  - Per layer: dual bf16 MFMA GEMM (xl = x@Wl, xr = x@Wr, fp32 accum/out),
//    then node-centric fused kernel (1 wave/node, online softmax, fused
//    bias+ELU, writes bf16 hidden state for the next layer's GEMM).
//  - Weights transposed+cast to bf16 [Mpad][K] once per call.

#define NFEAT 128
#define HID 256
#define NCLS 47
#define L2PAD 64

typedef __attribute__((ext_vector_type(8))) short bf16x8;
typedef __attribute__((ext_vector_type(4))) float f32x4;

__device__ __forceinline__ unsigned short f2b(float f) {
  unsigned int u = __builtin_bit_cast(unsigned int, f);
  u += 0x7FFFu + ((u >> 16) & 1u);  // round-to-nearest-even
  return (unsigned short)(u >> 16);
}

__device__ __forceinline__ float group8_sum(float v) {
  v += __shfl_xor(v, 1, 64);
  v += __shfl_xor(v, 2, 64);
  v += __shfl_xor(v, 4, 64);
  return v;
}

// ---------------- prep: casts / weight transpose ----------------
__global__ void k_cast_bf16(const float* __restrict__ in,
                            unsigned short* __restrict__ out, int n4) {
  int i = blockIdx.x * blockDim.x + threadIdx.x;
  if (i < n4) {
    float4 v = reinterpret_cast<const float4*>(in)[i];
    ushort4 o = {f2b(v.x), f2b(v.y), f2b(v.z), f2b(v.w)};
    reinterpret_cast<ushort4*>(out)[i] = o;
  }
}

// W [K][M] f32  ->  WT [Mpad][K] bf16 (zero-filled for m >= M)
__global__ void k_wt(const float* __restrict__ W, unsigned short* __restrict__ WT,
                     int K, int M, int Mpad) {
  int i = blockIdx.x * blockDim.x + threadIdx.x;
  if (i >= Mpad * K) return;
  int m = i / K, k = i - m * K;
  WT[i] = (m < M) ? f2b(W[(size_t)k * M + m]) : 0;
}

// ---------------- CSR build ----------------
__global__ void k_init_deg(int* __restrict__ deg, int n) {
  int i = blockIdx.x * blockDim.x + threadIdx.x;
  if (i < n) deg[i] = 1;  // implicit self-loop
}

__global__ void k_count(const int* __restrict__ dst, int* __restrict__ deg, int e) {
  int i = blockIdx.x * blockDim.x + threadIdx.x;
  if (i < e) atomicAdd(&deg[dst[i]], 1);
}

__global__ __launch_bounds__(1024) void k_scan(const int* __restrict__ deg,
                                               int* __restrict__ rowptr, int n) {
  __shared__ int sdata[1024];
  __shared__ int s_carry;
  int t = threadIdx.x;
  if (t == 0) { s_carry = 0; rowptr[0] = 0; }
  __syncthreads();
  for (int base = 0; base < n; base += 1024) {
    int i = base + t;
    int v = (i < n) ? deg[i] : 0;
    sdata[t] = v;
    __syncthreads();
    for (int off = 1; off < 1024; off <<= 1) {
      int add = (t >= off) ? sdata[t - off] : 0;
      __syncthreads();
      sdata[t] += add;
      __syncthreads();
    }
    int inc = sdata[t] + s_carry;
    if (i < n) rowptr[i + 1] = inc;
    __syncthreads();
    if (t == 1023) s_carry = inc;
    __syncthreads();
  }
}

__global__ void k_init_csr(const int* __restrict__ rowptr, int* __restrict__ adj,
                           int* __restrict__ cursor, int n) {
  int i = blockIdx.x * blockDim.x + threadIdx.x;
  if (i < n) { int p = rowptr[i]; adj[p] = i; cursor[i] = p + 1; }
}

__global__ void k_scatter(const int* __restrict__ src, const int* __restrict__ dst,
                          int* __restrict__ cursor, int* __restrict__ adj, int e) {
  int i = blockIdx.x * blockDim.x + threadIdx.x;
  if (i < e) { int p = atomicAdd(&cursor[dst[i]], 1); adj[p] = src[i]; }
}

// ---------------- dual bf16 MFMA GEMM ----------------
// X: [N][K] bf16 row-major. WlT/WrT: [Mpad][K] bf16 (i.e. W transposed).
// XL/XR: [N][Mpad] fp32. Tile 64(rows)x64(cols), BK=64, 4 waves: wave w owns
// rows [16w,16w+16) x 64 cols = 4 frags per output matrix.
__global__ __launch_bounds__(256) void gemm_dual_bf16(
    const unsigned short* __restrict__ X, const unsigned short* __restrict__ WlT,
    const unsigned short* __restrict__ WrT, float* __restrict__ XL,
    float* __restrict__ XR, int N, int K, int Mpad) {
  __shared__ __align__(16) unsigned short Xs[64][72];  // +8 pad vs bank conflicts
  __shared__ __align__(16) unsigned short Ls[64][72];
  __shared__ __align__(16) unsigned short Rs[64][72];

  const int t = threadIdx.x;
  const int row0 = blockIdx.x * 64;
  const int col0 = blockIdx.y * 64;
  const int w = t >> 6, lane = t & 63;
  const int r15 = lane & 15, kc = lane >> 4;

  f32x4 accL[4], accR[4];
  #pragma unroll
  for (int i = 0; i < 4; ++i) {
    accL[i] = (f32x4){0.f, 0.f, 0.f, 0.f};
    accR[i] = (f32x4){0.f, 0.f, 0.f, 0.f};
  }

  for (int k0 = 0; k0 < K; k0 += 64) {
    // stage X tile: 64 rows x 64 bf16 = 512 x 16B chunks, 2 per thread
    #pragma unroll
    for (int cc = 0; cc < 2; ++cc) {
      int c = t + cc * 256;
      int row = c >> 3, seg = (c & 7) * 8;
      int grow = row0 + row;
      if (grow < N) {
        *reinterpret_cast<uint4*>(&Xs[row][seg]) =
            *reinterpret_cast<const uint4*>(X + (size_t)grow * K + k0 + seg);
      } else {
        *reinterpret_cast<uint4*>(&Xs[row][seg]) = (uint4){0, 0, 0, 0};
      }
      // W tiles: col index always < Mpad (buffers padded)
      *reinterpret_cast<uint4*>(&Ls[row][seg]) =
          *reinterpret_cast<const uint4*>(WlT + (size_t)(col0 + row) * K + k0 + seg);
      *reinterpret_cast<uint4*>(&Rs[row][seg]) =
          *reinterpret_cast<const uint4*>(WrT + (size_t)(col0 + row) * K + k0 + seg);
    }
    __syncthreads();

    #pragma unroll
    for (int ks = 0; ks < 2; ++ks) {
      const bf16x8 a = *reinterpret_cast<const bf16x8*>(&Xs[16 * w + r15][ks * 32 + kc * 8]);
      #pragma unroll
      for (int nf = 0; nf < 4; ++nf) {
        const bf16x8 bl = *reinterpret_cast<const bf16x8*>(&Ls[nf * 16 + r15][ks * 32 + kc * 8]);
        const bf16x8 br = *reinterpret_cast<const bf16x8*>(&Rs[nf * 16 + r15][ks * 32 + kc * 8]);
        accL[nf] = __builtin_amdgcn_mfma_f32_16x16x32_bf16(a, bl, accL[nf], 0, 0, 0);
        accR[nf] = __builtin_amdgcn_mfma_f32_16x16x32_bf16(a, br, accR[nf], 0, 0, 0);
      }
    }
    __syncthreads();
  }

  // epilogue: C/D layout col=lane&15, row=(lane>>4)*4+reg  [HW-verified]
  #pragma unroll
  for (int nf = 0; nf < 4; ++nf) {
    int cc = col0 + nf * 16 + r15;
    #pragma unroll
    for (int i = 0; i < 4; ++i) {
      int rr = row0 + 16 * w + kc * 4 + i;
      if (rr < N) {
        XL[(size_t)rr * Mpad + cc] = accL[nf][i];
        XR[(size_t)rr * Mpad + cc] = accR[nf][i];
      }
    }
  }
}

// ---------------- fused node kernel, layers 0/1 (H=8, C=32) ----------------
// One wave per node; lane holds elems [4*lane,4*lane+4); head = lane>>3.
// Online softmax over incoming edges; bias+ELU epilogue; bf16 output.
__global__ __launch_bounds__(256) void gat_node_hc(
    const float* __restrict__ xl, const float* __restrict__ xr,
    const float* __restrict__ att, const float* __restrict__ bias,
    const int* __restrict__ rowptr, const int* __restrict__ adj,
    unsigned short* __restrict__ out, int n) {
  int wid = (blockIdx.x * blockDim.x + threadIdx.x) >> 6;
  int lane = threadIdx.x & 63;
  if (wid >= n) return;

  const float4 xrv = *reinterpret_cast<const float4*>(xr + (size_t)wid * HID + lane * 4);
  const float4 a = *reinterpret_cast<const float4*>(att + lane * 4);

  float m = -INFINITY, denom = 0.f;
  float4 acc = make_float4(0.f, 0.f, 0.f, 0.f);

  const int beg = rowptr[wid], end = rowptr[wid + 1];
  int u = adj[beg];
  for (int i = beg; i < end; ++i) {
    int unext = (i + 1 < end) ? adj[i + 1] : u;
    const float4 xlu = *reinterpret_cast<const float4*>(xl + (size_t)u * HID + lane * 4);
    float ex = xlu.x + xrv.x; ex = ex > 0.f ? ex : 0.2f * ex;
    float ey = xlu.y + xrv.y; ey = ey > 0.f ? ey : 0.2f * ey;
    float ez = xlu.z + xrv.z; ez = ez > 0.f ? ez : 0.2f * ez;
    float ew = xlu.w + xrv.w; ew = ew > 0.f ? ew : 0.2f * ew;
    float part = ex * a.x + ey * a.y + ez * a.z + ew * a.w;
    part = group8_sum(part);  // per-head logit (head = lane>>3)
    float mn = fmaxf(m, part);
    float so = __expf(m - mn);
    float wn = __expf(part - mn);
    denom = denom * so + wn;
    acc.x = acc.x * so + wn * xlu.x;
    acc.y = acc.y * so + wn * xlu.y;
    acc.z = acc.z * so + wn * xlu.z;
    acc.w = acc.w * so + wn * xlu.w;
    m = mn;
    u = unext;
  }

  const float inv = 1.f / (denom + 1e-16f);
  const float4 bv = *reinterpret_cast<const float4*>(bias + lane * 4);
  float o[4] = {acc.x * inv + bv.x, acc.y * inv + bv.y,
                acc.z * inv + bv.z, acc.w * inv + bv.w};
  #pragma unroll
  for (int j = 0; j < 4; ++j) o[j] = o[j] > 0.f ? o[j] : (__expf(o[j]) - 1.f);  // ELU
  ushort4 ov = {f2b(o[0]), f2b(o[1]), f2b(o[2]), f2b(o[3])};
  *reinterpret_cast<ushort4*>(out + (size_t)wid * HID + lane * 4) = ov;
}

// ---------------- fused node kernel, layer 2 (H=1, C=47) + log_softmax ----------------
// xl/xr stride L2PAD (padded GEMM output).
__global__ __launch_bounds__(256) void gat_node_l2(
    const float* __restrict__ xl, const float* __restrict__ xr,
    const float* __restrict__ att, const float* __restrict__ bias,
    const int* __restrict__ rowptr, const int* __restrict__ adj,
    float* __restrict__ out, int n) {
  int wid = (blockIdx.x * blockDim.x + threadIdx.x) >> 6;
  int lane = threadIdx.x & 63;
  if (wid >= n) return;
  const bool act = lane < NCLS;

  const float xrv = act ? xr[(size_t)wid * L2PAD + lane] : 0.f;
  const float a = act ? att[lane] : 0.f;

  float m = -INFINITY, denom = 0.f, acc = 0.f;
  const int beg = rowptr[wid], end = rowptr[wid + 1];
  int u = adj[beg];
  for (int i = beg; i < end; ++i) {
    int unext = (i + 1 < end) ? adj[i + 1] : u;
    float xlu = act ? xl[(size_t)u * L2PAD + lane] : 0.f;
    float e = xlu + xrv; e = e > 0.f ? e : 0.2f * e;
    float part = e * a;
    #pragma unroll
    for (int off = 1; off < 64; off <<= 1) part += __shfl_xor(part, off, 64);
    float mn = fmaxf(m, part);
    float so = __expf(m - mn);
    float wn = __expf(part - mn);
    denom = denom * so + wn;
    acc = acc * so + wn * xlu;
    m = mn;
    u = unext;
  }

  float r = acc / (denom + 1e-16f) + (act ? bias[lane] : 0.f);
  float rm = act ? r : -INFINITY;
  #pragma unroll
  for (int off = 1; off < 64; off <<= 1) rm = fmaxf(rm, __shfl_xor(rm, off, 64));
  float se = act ? __expf(r - rm) : 0.f;
  #pragma unroll
  for (int off = 1; off < 64; off <<= 1) se += __shfl_xor(se, off, 64);
  if (act) out[(size_t)wid * NCLS + lane] = r - rm - __logf(se);
}

// ---------------- launch ----------------
extern "C" void kernel_launch(void* const* d_in, const int* in_sizes, int n_in,
                              void* d_out, int out_size, void* d_ws, size_t ws_size,
                              hipStream_t stream) {
  const float* x   = (const float*)d_in[0];
  const int* ei    = (const int*)d_in[1];
  const float* Wl0 = (const float*)d_in[2];
  const float* Wr0 = (const float*)d_in[3];
  const float* a0  = (const float*)d_in[4];
  const float* b0  = (const float*)d_in[5];
  const float* Wl1 = (const float*)d_in[6];
  const float* Wr1 = (const float*)d_in[7];
  const float* a1  = (const float*)d_in[8];
  const float* b1  = (const float*)d_in[9];
  const float* Wl2 = (const float*)d_in[10];
  const float* Wr2 = (const float*)d_in[11];
  const float* a2  = (const float*)d_in[12];
  const float* b2  = (const float*)d_in[13];

  const int N = in_sizes[0] / NFEAT;   // 50000
  const int E = in_sizes[1] / 2;       // 800000
  const int* src = ei;
  const int* dst = ei + E;

  // workspace carve-up
  char* ws = (char*)d_ws;
  float* xl = (float*)ws;          ws += (size_t)N * HID * sizeof(float);   // 51.2 MB
  float* xr = (float*)ws;          ws += (size_t)N * HID * sizeof(float);   // 51.2 MB
  unsigned short* xb = (unsigned short*)ws; ws += (size_t)N * HID * sizeof(unsigned short); // 25.6 MB (holds x-bf16 then hidden)
  unsigned short* hb = (unsigned short*)ws; ws += (size_t)N * HID * sizeof(unsigned short); // 25.6 MB
  unsigned short* WT = (unsigned short*)ws; ws += (size_t)6 * HID * HID * sizeof(unsigned short); // 6x128KB
  int* deg    = (int*)ws;  ws += (size_t)N * sizeof(int);
  int* rowptr = (int*)ws;  ws += (size_t)(N + 1) * sizeof(int);
  int* adj    = (int*)ws;  ws += (size_t)(E + N) * sizeof(int);

  unsigned short* WlT0 = WT + 0 * HID * HID;
  unsigned short* WrT0 = WT + 1 * HID * HID;
  unsigned short* WlT1 = WT + 2 * HID * HID;
  unsigned short* WrT1 = WT + 3 * HID * HID;
  unsigned short* WlT2 = WT + 4 * HID * HID;
  unsigned short* WrT2 = WT + 5 * HID * HID;

  const int TB = 256;

  // --- prep: casts + weight transposes ---
  k_cast_bf16<<<(N * NFEAT / 4 + TB - 1) / TB, TB, 0, stream>>>(x, xb, N * NFEAT / 4);
  k_wt<<<(HID * NFEAT + TB - 1) / TB, TB, 0, stream>>>(Wl0, WlT0, NFEAT, HID, HID);
  k_wt<<<(HID * NFEAT + TB - 1) / TB, TB, 0, stream>>>(Wr0, WrT0, NFEAT, HID, HID);
  k_wt<<<(HID * HID + TB - 1) / TB, TB, 0, stream>>>(Wl1, WlT1, HID, HID, HID);
  k_wt<<<(HID * HID + TB - 1) / TB, TB, 0, stream>>>(Wr1, WrT1, HID, HID, HID);
  k_wt<<<(L2PAD * HID + TB - 1) / TB, TB, 0, stream>>>(Wl2, WlT2, HID, NCLS, L2PAD);
  k_wt<<<(L2PAD * HID + TB - 1) / TB, TB, 0, stream>>>(Wr2, WrT2, HID, NCLS, L2PAD);

  // --- CSR build ---
  k_init_deg<<<(N + TB - 1) / TB, TB, 0, stream>>>(deg, N);
  k_count<<<(E + TB - 1) / TB, TB, 0, stream>>>(dst, deg, E);
  k_scan<<<1, 1024, 0, stream>>>(deg, rowptr, N);
  k_init_csr<<<(N + TB - 1) / TB, TB, 0, stream>>>(rowptr, adj, deg, N);
  k_scatter<<<(E + TB - 1) / TB, TB, 0, stream>>>(src, dst, deg, adj, E);

  const int nodeBlocks = (N + 3) / 4;
  const int rowBlocks = (N + 63) / 64;

  // --- layer 0 ---
  {
    dim3 g(rowBlocks, HID / 64);
    gemm_dual_bf16<<<g, 256, 0, stream>>>(xb, WlT0, WrT0, xl, xr, N, NFEAT, HID);
    gat_node_hc<<<nodeBlocks, 256, 0, stream>>>(xl, xr, a0, b0, rowptr, adj, hb, N);
  }
  // --- layer 1 ---
  {
    dim3 g(rowBlocks, HID / 64);
    gemm_dual_bf16<<<g, 256, 0, stream>>>(hb, WlT1, WrT1, xl, xr, N, HID, HID);
    gat_node_hc<<<nodeBlocks, 256, 0, stream>>>(xl, xr, a1, b1, rowptr, adj, xb, N);
  }
  // --- layer 2 ---
  {
    dim3 g(rowBlocks, L2PAD / 64);
    gemm_dual_bf16<<<g, 256, 0, stream>>>(xb, WlT2, WrT2, xl, xr, N, HID, L2PAD);
    gat_node_l2<<<nodeBlocks, 256, 0, stream>>>(xl, xr, a2, b2, rowptr, adj,
                                                (float*)d_out, N);
  }
}

// Round 3
// 451.012 us; speedup vs baseline: 1.8672x; 1.3727x over previous
//
#include <hip/hip_runtime.h>
#include <cmath>

// GATv2 3-layer forward, round 2:
//  - bf16 MFMA GEMMs now write bf16 xl/xr (halves gather bytes + L3 footprint)
//  - node kernels: defer-max online softmax (fast path = 1 exp), 2-edge unroll
//  - hierarchical 3-phase scan for CSR build

#define NFEAT 128
#define HID 256
#define NCLS 47
#define L2PAD 64

typedef __attribute__((ext_vector_type(8))) short bf16x8;
typedef __attribute__((ext_vector_type(4))) float f32x4;

__device__ __forceinline__ unsigned short f2b(float f) {
  unsigned int u = __builtin_bit_cast(unsigned int, f);
  u += 0x7FFFu + ((u >> 16) & 1u);  // RNE
  return (unsigned short)(u >> 16);
}
__device__ __forceinline__ float b2f(unsigned short s) {
  return __builtin_bit_cast(float, (unsigned int)s << 16);
}
__device__ __forceinline__ float b2f_lo(unsigned int u) {
  return __builtin_bit_cast(float, u << 16);
}
__device__ __forceinline__ float b2f_hi(unsigned int u) {
  return __builtin_bit_cast(float, u & 0xFFFF0000u);
}

__device__ __forceinline__ float group8_sum(float v) {
  v += __shfl_xor(v, 1, 64);
  v += __shfl_xor(v, 2, 64);
  v += __shfl_xor(v, 4, 64);
  return v;
}

// ---------------- prep ----------------
__global__ void k_cast_bf16(const float* __restrict__ in,
                            unsigned short* __restrict__ out, int n4) {
  int i = blockIdx.x * blockDim.x + threadIdx.x;
  if (i < n4) {
    float4 v = reinterpret_cast<const float4*>(in)[i];
    ushort4 o = {f2b(v.x), f2b(v.y), f2b(v.z), f2b(v.w)};
    reinterpret_cast<ushort4*>(out)[i] = o;
  }
}

// W [K][M] f32 -> WT [Mpad][K] bf16
__global__ void k_wt(const float* __restrict__ W, unsigned short* __restrict__ WT,
                     int K, int M, int Mpad) {
  int i = blockIdx.x * blockDim.x + threadIdx.x;
  if (i >= Mpad * K) return;
  int m = i / K, k = i - m * K;
  WT[i] = (m < M) ? f2b(W[(size_t)k * M + m]) : 0;
}

// ---------------- CSR build ----------------
__global__ void k_init_deg(int* __restrict__ deg, int n) {
  int i = blockIdx.x * blockDim.x + threadIdx.x;
  if (i < n) deg[i] = 1;  // self-loop
}

__global__ void k_count(const int* __restrict__ dst, int* __restrict__ deg, int e) {
  int i = blockIdx.x * blockDim.x + threadIdx.x;
  if (i < e) atomicAdd(&deg[dst[i]], 1);
}

// phase 1: per-block (1024 elems) sums
__global__ __launch_bounds__(256) void k_bsum(const int* __restrict__ deg,
                                              int* __restrict__ bsum, int n) {
  int t = threadIdx.x;
  int base = blockIdx.x * 1024 + t * 4;
  int s = 0;
  if (base + 3 < n) {
    int4 v = *reinterpret_cast<const int4*>(deg + base);
    s = v.x + v.y + v.z + v.w;
  } else {
    for (int j = 0; j < 4; ++j) { int i = base + j; if (i < n) s += deg[i]; }
  }
  #pragma unroll
  for (int off = 1; off < 64; off <<= 1) s += __shfl_xor(s, off, 64);
  __shared__ int wsum[4];
  if ((t & 63) == 0) wsum[t >> 6] = s;
  __syncthreads();
  if (t == 0) bsum[blockIdx.x] = wsum[0] + wsum[1] + wsum[2] + wsum[3];
}

// phase 2: inclusive scan of <=64 block sums, single wave
__global__ void k_scanb(int* __restrict__ bsum, int nb) {
  int lane = threadIdx.x;
  int v = (lane < nb) ? bsum[lane] : 0;
  #pragma unroll
  for (int off = 1; off < 64; off <<= 1) {
    int u = __shfl_up(v, off, 64);
    if (lane >= off) v += u;
  }
  if (lane < nb) bsum[lane] = v;
}

// phase 3: rescan + write rowptr (rowptr[i+1] = inclusive prefix)
__global__ __launch_bounds__(256) void k_scanfinal(const int* __restrict__ deg,
                                                   const int* __restrict__ bscan,
                                                   int* __restrict__ rowptr, int n) {
  int t = threadIdx.x, b = blockIdx.x;
  int base = b * 1024 + t * 4;
  int v0 = 0, v1 = 0, v2 = 0, v3 = 0;
  if (base + 3 < n) {
    int4 v = *reinterpret_cast<const int4*>(deg + base);
    v0 = v.x; v1 = v.y; v2 = v.z; v3 = v.w;
  } else {
    if (base < n) v0 = deg[base];
    if (base + 1 < n) v1 = deg[base + 1];
    if (base + 2 < n) v2 = deg[base + 2];
    if (base + 3 < n) v3 = deg[base + 3];
  }
  int s = v0 + v1 + v2 + v3;
  int incl = s;
  #pragma unroll
  for (int off = 1; off < 64; off <<= 1) {
    int u = __shfl_up(incl, off, 64);
    if ((t & 63) >= off) incl += u;
  }
  __shared__ int wsum[4];
  int w = t >> 6, l = t & 63;
  if (l == 63) wsum[w] = incl;
  __syncthreads();
  int woff = 0;
  for (int j = 0; j < w; ++j) woff += wsum[j];
  int excl = incl - s + woff;
  int boff = (b == 0) ? 0 : bscan[b - 1];
  int p = boff + excl;
  if (base < n)     rowptr[base + 1] = p + v0;
  if (base + 1 < n) rowptr[base + 2] = p + v0 + v1;
  if (base + 2 < n) rowptr[base + 3] = p + v0 + v1 + v2;
  if (base + 3 < n) rowptr[base + 4] = p + v0 + v1 + v2 + v3;
  if (b == 0 && t == 0) rowptr[0] = 0;
}

__global__ void k_init_csr(const int* __restrict__ rowptr, int* __restrict__ adj,
                           int* __restrict__ cursor, int n) {
  int i = blockIdx.x * blockDim.x + threadIdx.x;
  if (i < n) { int p = rowptr[i]; adj[p] = i; cursor[i] = p + 1; }
}

__global__ void k_scatter(const int* __restrict__ src, const int* __restrict__ dst,
                          int* __restrict__ cursor, int* __restrict__ adj, int e) {
  int i = blockIdx.x * blockDim.x + threadIdx.x;
  if (i < e) { int p = atomicAdd(&cursor[dst[i]], 1); adj[p] = src[i]; }
}

// ---------------- dual bf16 MFMA GEMM (bf16 output) ----------------
// X: [N][K] bf16, WlT/WrT: [Mpad][K] bf16. XL/XR: [N][Mpad] bf16.
__global__ __launch_bounds__(256) void gemm_dual_bf16(
    const unsigned short* __restrict__ X, const unsigned short* __restrict__ WlT,
    const unsigned short* __restrict__ WrT, unsigned short* __restrict__ XL,
    unsigned short* __restrict__ XR, int N, int K, int Mpad) {
  __shared__ __align__(16) unsigned short Xs[64][72];
  __shared__ __align__(16) unsigned short Ls[64][72];
  __shared__ __align__(16) unsigned short Rs[64][72];

  const int t = threadIdx.x;
  const int row0 = blockIdx.x * 64;
  const int col0 = blockIdx.y * 64;
  const int w = t >> 6, lane = t & 63;
  const int r15 = lane & 15, kc = lane >> 4;

  f32x4 accL[4], accR[4];
  #pragma unroll
  for (int i = 0; i < 4; ++i) {
    accL[i] = (f32x4){0.f, 0.f, 0.f, 0.f};
    accR[i] = (f32x4){0.f, 0.f, 0.f, 0.f};
  }

  for (int k0 = 0; k0 < K; k0 += 64) {
    #pragma unroll
    for (int cc = 0; cc < 2; ++cc) {
      int c = t + cc * 256;
      int row = c >> 3, seg = (c & 7) * 8;
      int grow = row0 + row;
      if (grow < N) {
        *reinterpret_cast<uint4*>(&Xs[row][seg]) =
            *reinterpret_cast<const uint4*>(X + (size_t)grow * K + k0 + seg);
      } else {
        *reinterpret_cast<uint4*>(&Xs[row][seg]) = (uint4){0, 0, 0, 0};
      }
      *reinterpret_cast<uint4*>(&Ls[row][seg]) =
          *reinterpret_cast<const uint4*>(WlT + (size_t)(col0 + row) * K + k0 + seg);
      *reinterpret_cast<uint4*>(&Rs[row][seg]) =
          *reinterpret_cast<const uint4*>(WrT + (size_t)(col0 + row) * K + k0 + seg);
    }
    __syncthreads();

    #pragma unroll
    for (int ks = 0; ks < 2; ++ks) {
      const bf16x8 a = *reinterpret_cast<const bf16x8*>(&Xs[16 * w + r15][ks * 32 + kc * 8]);
      #pragma unroll
      for (int nf = 0; nf < 4; ++nf) {
        const bf16x8 bl = *reinterpret_cast<const bf16x8*>(&Ls[nf * 16 + r15][ks * 32 + kc * 8]);
        const bf16x8 br = *reinterpret_cast<const bf16x8*>(&Rs[nf * 16 + r15][ks * 32 + kc * 8]);
        accL[nf] = __builtin_amdgcn_mfma_f32_16x16x32_bf16(a, bl, accL[nf], 0, 0, 0);
        accR[nf] = __builtin_amdgcn_mfma_f32_16x16x32_bf16(a, br, accR[nf], 0, 0, 0);
      }
    }
    __syncthreads();
  }

  // C/D layout: col=lane&15, row=(lane>>4)*4+reg
  #pragma unroll
  for (int nf = 0; nf < 4; ++nf) {
    int cc = col0 + nf * 16 + r15;
    #pragma unroll
    for (int i = 0; i < 4; ++i) {
      int rr = row0 + 16 * w + kc * 4 + i;
      if (rr < N) {
        XL[(size_t)rr * Mpad + cc] = f2b(accL[nf][i]);
        XR[(size_t)rr * Mpad + cc] = f2b(accR[nf][i]);
      }
    }
  }
}

// ---------------- fused node kernel, layers 0/1 (H=8, C=32) ----------------
// 1 wave/node, lane holds elems [4*lane,4*lane+4), head = lane>>3.
// bf16 xl/xr; defer-max online softmax; 2-edge unroll; bias+ELU; bf16 out.
__global__ __launch_bounds__(256) void gat_node_hc(
    const unsigned short* __restrict__ xl, const unsigned short* __restrict__ xr,
    const float* __restrict__ att, const float* __restrict__ bias,
    const int* __restrict__ rowptr, const int* __restrict__ adj,
    unsigned short* __restrict__ out, int n) {
  int wid = (blockIdx.x * blockDim.x + threadIdx.x) >> 6;
  int lane = threadIdx.x & 63;
  if (wid >= n) return;

  uint2 pr = *reinterpret_cast<const uint2*>(xr + (size_t)wid * HID + lane * 4);
  const float xr0 = b2f_lo(pr.x), xr1 = b2f_hi(pr.x);
  const float xr2 = b2f_lo(pr.y), xr3 = b2f_hi(pr.y);
  const float4 a = *reinterpret_cast<const float4*>(att + lane * 4);

  float m = -INFINITY, denom = 0.f;
  float a0 = 0.f, a1 = 0.f, a2 = 0.f, a3 = 0.f;

#define EDGE_PREP(p, x0, x1, x2, x3, part)                                 \
  x0 = b2f_lo(p.x); x1 = b2f_hi(p.x); x2 = b2f_lo(p.y); x3 = b2f_hi(p.y);  \
  {                                                                        \
    float t0 = x0 + xr0, t1 = x1 + xr1, t2 = x2 + xr2, t3 = x3 + xr3;      \
    t0 = fmaxf(t0, 0.2f * t0); t1 = fmaxf(t1, 0.2f * t1);                  \
    t2 = fmaxf(t2, 0.2f * t2); t3 = fmaxf(t3, 0.2f * t3);                  \
    part = t0 * a.x + t1 * a.y + t2 * a.z + t3 * a.w;                      \
    part = group8_sum(part);                                               \
  }

#define SLOW_UPDATE(part, x0, x1, x2, x3)                                  \
  {                                                                        \
    float mn = fmaxf(m, part);                                             \
    float so = __expf(m - mn);                                             \
    float wn = __expf(part - mn);                                          \
    denom = denom * so + wn;                                               \
    a0 = a0 * so + wn * x0; a1 = a1 * so + wn * x1;                        \
    a2 = a2 * so + wn * x2; a3 = a3 * so + wn * x3;                        \
    m = mn;                                                                \
  }

  const int beg = rowptr[wid], end = rowptr[wid + 1];
  int i = beg;
  for (; i + 1 < end; i += 2) {
    int u0 = adj[i], u1 = adj[i + 1];
    uint2 p0 = *reinterpret_cast<const uint2*>(xl + (size_t)u0 * HID + lane * 4);
    uint2 p1 = *reinterpret_cast<const uint2*>(xl + (size_t)u1 * HID + lane * 4);
    float x00, x01, x02, x03, part0;
    float x10, x11, x12, x13, part1;
    EDGE_PREP(p0, x00, x01, x02, x03, part0);
    EDGE_PREP(p1, x10, x11, x12, x13, part1);
    float mx = fmaxf(part0, part1);
    if (__any(mx > m + 8.f)) {
      SLOW_UPDATE(part0, x00, x01, x02, x03);
      SLOW_UPDATE(part1, x10, x11, x12, x13);
    } else {
      float w0 = __expf(part0 - m), w1 = __expf(part1 - m);
      denom += w0 + w1;
      a0 += w0 * x00 + w1 * x10; a1 += w0 * x01 + w1 * x11;
      a2 += w0 * x02 + w1 * x12; a3 += w0 * x03 + w1 * x13;
    }
  }
  if (i < end) {
    int u0 = adj[i];
    uint2 p0 = *reinterpret_cast<const uint2*>(xl + (size_t)u0 * HID + lane * 4);
    float x00, x01, x02, x03, part0;
    EDGE_PREP(p0, x00, x01, x02, x03, part0);
    if (__any(part0 > m + 8.f)) {
      SLOW_UPDATE(part0, x00, x01, x02, x03);
    } else {
      float w0 = __expf(part0 - m);
      denom += w0;
      a0 += w0 * x00; a1 += w0 * x01; a2 += w0 * x02; a3 += w0 * x03;
    }
  }
#undef EDGE_PREP
#undef SLOW_UPDATE

  const float inv = 1.f / (denom + 1e-16f);
  const float4 bv = *reinterpret_cast<const float4*>(bias + lane * 4);
  float o[4] = {a0 * inv + bv.x, a1 * inv + bv.y, a2 * inv + bv.z, a3 * inv + bv.w};
  #pragma unroll
  for (int j = 0; j < 4; ++j) o[j] = o[j] > 0.f ? o[j] : (__expf(o[j]) - 1.f);  // ELU
  ushort4 ov = {f2b(o[0]), f2b(o[1]), f2b(o[2]), f2b(o[3])};
  *reinterpret_cast<ushort4*>(out + (size_t)wid * HID + lane * 4) = ov;
}

// ---------------- fused node kernel, layer 2 (H=1, C=47) + log_softmax ----------------
__global__ __launch_bounds__(256) void gat_node_l2(
    const unsigned short* __restrict__ xl, const unsigned short* __restrict__ xr,
    const float* __restrict__ att, const float* __restrict__ bias,
    const int* __restrict__ rowptr, const int* __restrict__ adj,
    float* __restrict__ out, int n) {
  int wid = (blockIdx.x * blockDim.x + threadIdx.x) >> 6;
  int lane = threadIdx.x & 63;
  if (wid >= n) return;
  const bool act = lane < NCLS;

  const float xrv = act ? b2f(xr[(size_t)wid * L2PAD + lane]) : 0.f;
  const float a = act ? att[lane] : 0.f;

  float m = -INFINITY, denom = 0.f, acc = 0.f;

#define L2_PREP(u, xv, part)                                               \
  xv = act ? b2f(xl[(size_t)(u) * L2PAD + lane]) : 0.f;                    \
  {                                                                        \
    float e = xv + xrv; e = fmaxf(e, 0.2f * e);                            \
    part = e * a;                                                          \
    _Pragma("unroll")                                                      \
    for (int off = 1; off < 64; off <<= 1) part += __shfl_xor(part, off, 64); \
  }

#define L2_SLOW(part, xv)                                                  \
  {                                                                        \
    float mn = fmaxf(m, part);                                             \
    float so = __expf(m - mn);                                             \
    float wn = __expf(part - mn);                                          \
    denom = denom * so + wn;                                               \
    acc = acc * so + wn * xv;                                              \
    m = mn;                                                                \
  }

  const int beg = rowptr[wid], end = rowptr[wid + 1];
  int i = beg;
  for (; i + 1 < end; i += 2) {
    int u0 = adj[i], u1 = adj[i + 1];
    float xv0, part0, xv1, part1;
    L2_PREP(u0, xv0, part0);
    L2_PREP(u1, xv1, part1);
    float mx = fmaxf(part0, part1);
    if (mx > m + 8.f) {  // wave-uniform (all lanes share part)
      L2_SLOW(part0, xv0);
      L2_SLOW(part1, xv1);
    } else {
      float w0 = __expf(part0 - m), w1 = __expf(part1 - m);
      denom += w0 + w1;
      acc += w0 * xv0 + w1 * xv1;
    }
  }
  if (i < end) {
    int u0 = adj[i];
    float xv0, part0;
    L2_PREP(u0, xv0, part0);
    if (part0 > m + 8.f) {
      L2_SLOW(part0, xv0);
    } else {
      float w0 = __expf(part0 - m);
      denom += w0;
      acc += w0 * xv0;
    }
  }
#undef L2_PREP
#undef L2_SLOW

  float r = acc / (denom + 1e-16f) + (act ? bias[lane] : 0.f);
  float rm = act ? r : -INFINITY;
  #pragma unroll
  for (int off = 1; off < 64; off <<= 1) rm = fmaxf(rm, __shfl_xor(rm, off, 64));
  float se = act ? __expf(r - rm) : 0.f;
  #pragma unroll
  for (int off = 1; off < 64; off <<= 1) se += __shfl_xor(se, off, 64);
  if (act) out[(size_t)wid * NCLS + lane] = r - rm - __logf(se);
}

// ---------------- launch ----------------
extern "C" void kernel_launch(void* const* d_in, const int* in_sizes, int n_in,
                              void* d_out, int out_size, void* d_ws, size_t ws_size,
                              hipStream_t stream) {
  const float* x   = (const float*)d_in[0];
  const int* ei    = (const int*)d_in[1];
  const float* Wl0 = (const float*)d_in[2];
  const float* Wr0 = (const float*)d_in[3];
  const float* a0  = (const float*)d_in[4];
  const float* b0  = (const float*)d_in[5];
  const float* Wl1 = (const float*)d_in[6];
  const float* Wr1 = (const float*)d_in[7];
  const float* a1  = (const float*)d_in[8];
  const float* b1  = (const float*)d_in[9];
  const float* Wl2 = (const float*)d_in[10];
  const float* Wr2 = (const float*)d_in[11];
  const float* a2  = (const float*)d_in[12];
  const float* b2  = (const float*)d_in[13];

  const int N = in_sizes[0] / NFEAT;   // 50000
  const int E = in_sizes[1] / 2;       // 800000
  const int* src = ei;
  const int* dst = ei + E;

  // workspace carve-up (~120 MB)
  char* ws = (char*)d_ws;
  unsigned short* xlb = (unsigned short*)ws; ws += (size_t)N * HID * 2;   // 25.6 MB
  unsigned short* xrb = (unsigned short*)ws; ws += (size_t)N * HID * 2;   // 25.6 MB
  unsigned short* xb  = (unsigned short*)ws; ws += (size_t)N * NFEAT * 2; // 12.8 MB
  unsigned short* hb  = (unsigned short*)ws; ws += (size_t)N * HID * 2;   // 25.6 MB
  unsigned short* hb2 = (unsigned short*)ws; ws += (size_t)N * HID * 2;   // 25.6 MB
  unsigned short* WT  = (unsigned short*)ws; ws += (size_t)6 * HID * HID * 2;
  int* deg    = (int*)ws; ws += (size_t)N * sizeof(int);
  int* rowptr = (int*)ws; ws += (size_t)(N + 8) * sizeof(int);
  int* bsum   = (int*)ws; ws += (size_t)64 * sizeof(int);
  int* adj    = (int*)ws; ws += (size_t)(E + N) * sizeof(int);

  unsigned short* WlT0 = WT + 0 * HID * HID;
  unsigned short* WrT0 = WT + 1 * HID * HID;
  unsigned short* WlT1 = WT + 2 * HID * HID;
  unsigned short* WrT1 = WT + 3 * HID * HID;
  unsigned short* WlT2 = WT + 4 * HID * HID;
  unsigned short* WrT2 = WT + 5 * HID * HID;

  const int TB = 256;
  const int nbScan = (N + 1023) / 1024;  // 49 <= 64

  // --- prep ---
  k_cast_bf16<<<(N * NFEAT / 4 + TB - 1) / TB, TB, 0, stream>>>(x, xb, N * NFEAT / 4);
  k_wt<<<(HID * NFEAT + TB - 1) / TB, TB, 0, stream>>>(Wl0, WlT0, NFEAT, HID, HID);
  k_wt<<<(HID * NFEAT + TB - 1) / TB, TB, 0, stream>>>(Wr0, WrT0, NFEAT, HID, HID);
  k_wt<<<(HID * HID + TB - 1) / TB, TB, 0, stream>>>(Wl1, WlT1, HID, HID, HID);
  k_wt<<<(HID * HID + TB - 1) / TB, TB, 0, stream>>>(Wr1, WrT1, HID, HID, HID);
  k_wt<<<(L2PAD * HID + TB - 1) / TB, TB, 0, stream>>>(Wl2, WlT2, HID, NCLS, L2PAD);
  k_wt<<<(L2PAD * HID + TB - 1) / TB, TB, 0, stream>>>(Wr2, WrT2, HID, NCLS, L2PAD);

  // --- CSR build ---
  k_init_deg<<<(N + TB - 1) / TB, TB, 0, stream>>>(deg, N);
  k_count<<<(E + TB - 1) / TB, TB, 0, stream>>>(dst, deg, E);
  k_bsum<<<nbScan, TB, 0, stream>>>(deg, bsum, N);
  k_scanb<<<1, 64, 0, stream>>>(bsum, nbScan);
  k_scanfinal<<<nbScan, TB, 0, stream>>>(deg, bsum, rowptr, N);
  k_init_csr<<<(N + TB - 1) / TB, TB, 0, stream>>>(rowptr, adj, deg, N);
  k_scatter<<<(E + TB - 1) / TB, TB, 0, stream>>>(src, dst, deg, adj, E);

  const int nodeBlocks = (N + 3) / 4;
  const int rowBlocks = (N + 63) / 64;

  // --- layer 0 ---
  {
    dim3 g(rowBlocks, HID / 64);
    gemm_dual_bf16<<<g, 256, 0, stream>>>(xb, WlT0, WrT0, xlb, xrb, N, NFEAT, HID);
    gat_node_hc<<<nodeBlocks, 256, 0, stream>>>(xlb, xrb, a0, b0, rowptr, adj, hb, N);
  }
  // --- layer 1 ---
  {
    dim3 g(rowBlocks, HID / 64);
    gemm_dual_bf16<<<g, 256, 0, stream>>>(hb, WlT1, WrT1, xlb, xrb, N, HID, HID);
    gat_node_hc<<<nodeBlocks, 256, 0, stream>>>(xlb, xrb, a1, b1, rowptr, adj, hb2, N);
  }
  // --- layer 2 ---
  {
    dim3 g(rowBlocks, 1);
    gemm_dual_bf16<<<g, 256, 0, stream>>>(hb2, WlT2, WrT2, xlb, xrb, N, HID, L2PAD);
    gat_node_l2<<<nodeBlocks, 256, 0, stream>>>(xlb, xrb, a2, b2, rowptr, adj,
                                                (float*)d_out, N);
  }
}

// Round 4
// 445.129 us; speedup vs baseline: 1.8919x; 1.0132x over previous
//
#include <hip/hip_runtime.h>
#include <cmath>

// GATv2 3-layer forward, round 3:
//  - layer2 split: edge-parallel logit kernel (lane=edge, no shuffles) +
//    max-first aggregation (shuffle-free inner loop)
//  - hc node kernel: 8 values/lane (uint4), 2 edges per wave iteration
//    (independent half-wave online softmax, merged at end), float2 math
//    to target v_pk_*_f32

#define NFEAT 128
#define HID 256
#define NCLS 47
#define L2PAD 64

typedef __attribute__((ext_vector_type(8))) short bf16x8;
typedef __attribute__((ext_vector_type(4))) float f32x4;
typedef __attribute__((ext_vector_type(2))) float f32x2;

__device__ __forceinline__ unsigned short f2b(float f) {
  unsigned int u = __builtin_bit_cast(unsigned int, f);
  u += 0x7FFFu + ((u >> 16) & 1u);  // RNE
  return (unsigned short)(u >> 16);
}
__device__ __forceinline__ float b2f(unsigned short s) {
  return __builtin_bit_cast(float, (unsigned int)s << 16);
}
__device__ __forceinline__ f32x2 b2f2(unsigned int u) {
  return (f32x2){__builtin_bit_cast(float, u << 16),
                 __builtin_bit_cast(float, u & 0xFFFF0000u)};
}

// ---------------- prep ----------------
__global__ void k_cast_bf16(const float* __restrict__ in,
                            unsigned short* __restrict__ out, int n4) {
  int i = blockIdx.x * blockDim.x + threadIdx.x;
  if (i < n4) {
    float4 v = reinterpret_cast<const float4*>(in)[i];
    ushort4 o = {f2b(v.x), f2b(v.y), f2b(v.z), f2b(v.w)};
    reinterpret_cast<ushort4*>(out)[i] = o;
  }
}

// W [K][M] f32 -> WT [Mpad][K] bf16
__global__ void k_wt(const float* __restrict__ W, unsigned short* __restrict__ WT,
                     int K, int M, int Mpad) {
  int i = blockIdx.x * blockDim.x + threadIdx.x;
  if (i >= Mpad * K) return;
  int m = i / K, k = i - m * K;
  WT[i] = (m < M) ? f2b(W[(size_t)k * M + m]) : 0;
}

__global__ void k_pad_att(const float* __restrict__ a, float* __restrict__ out48) {
  int i = threadIdx.x;
  if (i < 48) out48[i] = (i < NCLS) ? a[i] : 0.f;
}

// ---------------- CSR build ----------------
__global__ void k_init_deg(int* __restrict__ deg, int n) {
  int i = blockIdx.x * blockDim.x + threadIdx.x;
  if (i < n) deg[i] = 1;  // self-loop
}

__global__ void k_count(const int* __restrict__ dst, int* __restrict__ deg, int e) {
  int i = blockIdx.x * blockDim.x + threadIdx.x;
  if (i < e) atomicAdd(&deg[dst[i]], 1);
}

__global__ __launch_bounds__(256) void k_bsum(const int* __restrict__ deg,
                                              int* __restrict__ bsum, int n) {
  int t = threadIdx.x;
  int base = blockIdx.x * 1024 + t * 4;
  int s = 0;
  if (base + 3 < n) {
    int4 v = *reinterpret_cast<const int4*>(deg + base);
    s = v.x + v.y + v.z + v.w;
  } else {
    for (int j = 0; j < 4; ++j) { int i = base + j; if (i < n) s += deg[i]; }
  }
  #pragma unroll
  for (int off = 1; off < 64; off <<= 1) s += __shfl_xor(s, off, 64);
  __shared__ int wsum[4];
  if ((t & 63) == 0) wsum[t >> 6] = s;
  __syncthreads();
  if (t == 0) bsum[blockIdx.x] = wsum[0] + wsum[1] + wsum[2] + wsum[3];
}

__global__ void k_scanb(int* __restrict__ bsum, int nb) {
  int lane = threadIdx.x;
  int v = (lane < nb) ? bsum[lane] : 0;
  #pragma unroll
  for (int off = 1; off < 64; off <<= 1) {
    int u = __shfl_up(v, off, 64);
    if (lane >= off) v += u;
  }
  if (lane < nb) bsum[lane] = v;
}

__global__ __launch_bounds__(256) void k_scanfinal(const int* __restrict__ deg,
                                                   const int* __restrict__ bscan,
                                                   int* __restrict__ rowptr, int n) {
  int t = threadIdx.x, b = blockIdx.x;
  int base = b * 1024 + t * 4;
  int v0 = 0, v1 = 0, v2 = 0, v3 = 0;
  if (base + 3 < n) {
    int4 v = *reinterpret_cast<const int4*>(deg + base);
    v0 = v.x; v1 = v.y; v2 = v.z; v3 = v.w;
  } else {
    if (base < n) v0 = deg[base];
    if (base + 1 < n) v1 = deg[base + 1];
    if (base + 2 < n) v2 = deg[base + 2];
    if (base + 3 < n) v3 = deg[base + 3];
  }
  int s = v0 + v1 + v2 + v3;
  int incl = s;
  #pragma unroll
  for (int off = 1; off < 64; off <<= 1) {
    int u = __shfl_up(incl, off, 64);
    if ((t & 63) >= off) incl += u;
  }
  __shared__ int wsum[4];
  int w = t >> 6, l = t & 63;
  if (l == 63) wsum[w] = incl;
  __syncthreads();
  int woff = 0;
  for (int j = 0; j < w; ++j) woff += wsum[j];
  int excl = incl - s + woff;
  int boff = (b == 0) ? 0 : bscan[b - 1];
  int p = boff + excl;
  if (base < n)     rowptr[base + 1] = p + v0;
  if (base + 1 < n) rowptr[base + 2] = p + v0 + v1;
  if (base + 2 < n) rowptr[base + 3] = p + v0 + v1 + v2;
  if (base + 3 < n) rowptr[base + 4] = p + v0 + v1 + v2 + v3;
  if (b == 0 && t == 0) rowptr[0] = 0;
}

__global__ void k_init_csr(const int* __restrict__ rowptr, int* __restrict__ adj,
                           int* __restrict__ vdst, int* __restrict__ cursor, int n) {
  int i = blockIdx.x * blockDim.x + threadIdx.x;
  if (i < n) { int p = rowptr[i]; adj[p] = i; vdst[p] = i; cursor[i] = p + 1; }
}

__global__ void k_scatter(const int* __restrict__ src, const int* __restrict__ dst,
                          int* __restrict__ cursor, int* __restrict__ adj,
                          int* __restrict__ vdst, int e) {
  int i = blockIdx.x * blockDim.x + threadIdx.x;
  if (i < e) {
    int d = dst[i];
    int p = atomicAdd(&cursor[d], 1);
    adj[p] = src[i];
    vdst[p] = d;
  }
}

// ---------------- dual bf16 MFMA GEMM (bf16 output) ----------------
__global__ __launch_bounds__(256) void gemm_dual_bf16(
    const unsigned short* __restrict__ X, const unsigned short* __restrict__ WlT,
    const unsigned short* __restrict__ WrT, unsigned short* __restrict__ XL,
    unsigned short* __restrict__ XR, int N, int K, int Mpad) {
  __shared__ __align__(16) unsigned short Xs[64][72];
  __shared__ __align__(16) unsigned short Ls[64][72];
  __shared__ __align__(16) unsigned short Rs[64][72];

  const int t = threadIdx.x;
  const int row0 = blockIdx.x * 64;
  const int col0 = blockIdx.y * 64;
  const int w = t >> 6, lane = t & 63;
  const int r15 = lane & 15, kc = lane >> 4;

  f32x4 accL[4], accR[4];
  #pragma unroll
  for (int i = 0; i < 4; ++i) {
    accL[i] = (f32x4){0.f, 0.f, 0.f, 0.f};
    accR[i] = (f32x4){0.f, 0.f, 0.f, 0.f};
  }

  for (int k0 = 0; k0 < K; k0 += 64) {
    #pragma unroll
    for (int cc = 0; cc < 2; ++cc) {
      int c = t + cc * 256;
      int row = c >> 3, seg = (c & 7) * 8;
      int grow = row0 + row;
      if (grow < N) {
        *reinterpret_cast<uint4*>(&Xs[row][seg]) =
            *reinterpret_cast<const uint4*>(X + (size_t)grow * K + k0 + seg);
      } else {
        *reinterpret_cast<uint4*>(&Xs[row][seg]) = (uint4){0, 0, 0, 0};
      }
      *reinterpret_cast<uint4*>(&Ls[row][seg]) =
          *reinterpret_cast<const uint4*>(WlT + (size_t)(col0 + row) * K + k0 + seg);
      *reinterpret_cast<uint4*>(&Rs[row][seg]) =
          *reinterpret_cast<const uint4*>(WrT + (size_t)(col0 + row) * K + k0 + seg);
    }
    __syncthreads();

    #pragma unroll
    for (int ks = 0; ks < 2; ++ks) {
      const bf16x8 a = *reinterpret_cast<const bf16x8*>(&Xs[16 * w + r15][ks * 32 + kc * 8]);
      #pragma unroll
      for (int nf = 0; nf < 4; ++nf) {
        const bf16x8 bl = *reinterpret_cast<const bf16x8*>(&Ls[nf * 16 + r15][ks * 32 + kc * 8]);
        const bf16x8 br = *reinterpret_cast<const bf16x8*>(&Rs[nf * 16 + r15][ks * 32 + kc * 8]);
        accL[nf] = __builtin_amdgcn_mfma_f32_16x16x32_bf16(a, bl, accL[nf], 0, 0, 0);
        accR[nf] = __builtin_amdgcn_mfma_f32_16x16x32_bf16(a, br, accR[nf], 0, 0, 0);
      }
    }
    __syncthreads();
  }

  #pragma unroll
  for (int nf = 0; nf < 4; ++nf) {
    int cc = col0 + nf * 16 + r15;
    #pragma unroll
    for (int i = 0; i < 4; ++i) {
      int rr = row0 + 16 * w + kc * 4 + i;
      if (rr < N) {
        XL[(size_t)rr * Mpad + cc] = f2b(accL[nf][i]);
        XR[(size_t)rr * Mpad + cc] = f2b(accR[nf][i]);
      }
    }
  }
}

// ---------------- fused node kernel, layers 0/1 (H=8, C=32) ----------------
// 1 wave/node; lane = (half = lane>>5, slot q = lane&31); slot q holds values
// [8q, 8q+8). Half h processes edges beg+2t+h: independent online softmax per
// half, flash-style merge at the end. Head = q>>2; reduce = 2 shfls.
__global__ __launch_bounds__(256) void gat_node_hc(
    const unsigned short* __restrict__ xl, const unsigned short* __restrict__ xr,
    const float* __restrict__ att, const float* __restrict__ bias,
    const int* __restrict__ rowptr, const int* __restrict__ adj,
    unsigned short* __restrict__ out, int n) {
  int wid = (blockIdx.x * blockDim.x + threadIdx.x) >> 6;
  int lane = threadIdx.x & 63;
  if (wid >= n) return;
  const int q = lane & 31, half = lane >> 5;

  const uint4 xrp = *reinterpret_cast<const uint4*>(xr + (size_t)wid * HID + q * 8);
  const f32x2 xr2[4] = {b2f2(xrp.x), b2f2(xrp.y), b2f2(xrp.z), b2f2(xrp.w)};
  const float4 af0 = *reinterpret_cast<const float4*>(att + q * 8);
  const float4 af1 = *reinterpret_cast<const float4*>(att + q * 8 + 4);
  const f32x2 a2[4] = {{af0.x, af0.y}, {af0.z, af0.w},
                       {af1.x, af1.y}, {af1.z, af1.w}};

  float m = -1e30f, denom = 0.f;
  f32x2 acc[4] = {{0.f, 0.f}, {0.f, 0.f}, {0.f, 0.f}, {0.f, 0.f}};

  const int beg = rowptr[wid], end = rowptr[wid + 1];
  for (int base = beg; base < end; base += 2) {
    const int i = base + half;
    const bool act = i < end;
    const int u = adj[act ? i : base];
    const uint4 p = *reinterpret_cast<const uint4*>(xl + (size_t)u * HID + q * 8);
    const f32x2 x2[4] = {b2f2(p.x), b2f2(p.y), b2f2(p.z), b2f2(p.w)};
    f32x2 s2 = x2[0] * 0.f;
    #pragma unroll
    for (int j = 0; j < 4; ++j) {
      f32x2 z = x2[j] + xr2[j];
      f32x2 lz = 0.2f * z;
      f32x2 r = {fmaxf(z.x, lz.x), fmaxf(z.y, lz.y)};
      s2 += r * a2[j];
    }
    float part = s2.x + s2.y;
    part += __shfl_xor(part, 1, 64);
    part += __shfl_xor(part, 2, 64);
    if (!act) part = -1e30f;
    if (__any(part > m + 8.f)) {
      float mn = fmaxf(m, part);
      float so = __expf(m - mn);
      float wn = act ? __expf(part - mn) : 0.f;
      denom = denom * so + wn;
      #pragma unroll
      for (int j = 0; j < 4; ++j) acc[j] = acc[j] * so + wn * x2[j];
      m = mn;
    } else {
      float wn = act ? __expf(part - m) : 0.f;
      denom += wn;
      #pragma unroll
      for (int j = 0; j < 4; ++j) acc[j] += wn * x2[j];
    }
  }

  // merge the two half-wave softmax states (same node, same head layout)
  float mo = __shfl_xor(m, 32, 64);
  float ms = fmaxf(m, mo);
  float sc = __expf(m - ms);
  denom *= sc;
  denom += __shfl_xor(denom, 32, 64);
  #pragma unroll
  for (int j = 0; j < 4; ++j) {
    acc[j] *= sc;
    acc[j].x += __shfl_xor(acc[j].x, 32, 64);
    acc[j].y += __shfl_xor(acc[j].y, 32, 64);
  }

  if (half == 0) {
    const float inv = 1.f / (denom + 1e-16f);
    const float4 bf0 = *reinterpret_cast<const float4*>(bias + q * 8);
    const float4 bf1 = *reinterpret_cast<const float4*>(bias + q * 8 + 4);
    float o[8] = {acc[0].x * inv + bf0.x, acc[0].y * inv + bf0.y,
                  acc[1].x * inv + bf0.z, acc[1].y * inv + bf0.w,
                  acc[2].x * inv + bf1.x, acc[2].y * inv + bf1.y,
                  acc[3].x * inv + bf1.z, acc[3].y * inv + bf1.w};
    #pragma unroll
    for (int j = 0; j < 8; ++j) o[j] = o[j] > 0.f ? o[j] : (__expf(o[j]) - 1.f);
    uint4 ov;
    ov.x = (unsigned)f2b(o[0]) | ((unsigned)f2b(o[1]) << 16);
    ov.y = (unsigned)f2b(o[2]) | ((unsigned)f2b(o[3]) << 16);
    ov.z = (unsigned)f2b(o[4]) | ((unsigned)f2b(o[5]) << 16);
    ov.w = (unsigned)f2b(o[6]) | ((unsigned)f2b(o[7]) << 16);
    *reinterpret_cast<uint4*>(out + (size_t)wid * HID + q * 8) = ov;
  }
}

// ---------------- layer-2 edge logits (lane = CSR slot) ----------------
__global__ __launch_bounds__(256) void k_logit_l2(
    const unsigned short* __restrict__ xl, const unsigned short* __restrict__ xr,
    const float* __restrict__ att48, const int* __restrict__ adj,
    const int* __restrict__ vdst, float* __restrict__ logit, int total) {
  int i = blockIdx.x * blockDim.x + threadIdx.x;
  if (i >= total) return;
  const int u = adj[i], v = vdst[i];
  const uint4* pu = reinterpret_cast<const uint4*>(xl + (size_t)u * L2PAD);
  const uint4* pv = reinterpret_cast<const uint4*>(xr + (size_t)v * L2PAD);
  f32x2 s2 = {0.f, 0.f};
  #pragma unroll
  for (int b = 0; b < 6; ++b) {  // 6 x 8 = 48 values (47 real + 1 zero pad)
    const uint4 xu = pu[b], xv = pv[b];
    const f32x2* a2 = reinterpret_cast<const f32x2*>(att48 + b * 8);
    const unsigned ua[4] = {xu.x, xu.y, xu.z, xu.w};
    const unsigned va[4] = {xv.x, xv.y, xv.z, xv.w};
    #pragma unroll
    for (int j = 0; j < 4; ++j) {
      f32x2 z = b2f2(ua[j]) + b2f2(va[j]);
      f32x2 lz = 0.2f * z;
      f32x2 r = {fmaxf(z.x, lz.x), fmaxf(z.y, lz.y)};
      s2 += r * a2[j];
    }
  }
  logit[i] = s2.x + s2.y;
}

// ---------------- layer-2 aggregation + log_softmax ----------------
__global__ __launch_bounds__(256) void gat_node_l2(
    const unsigned short* __restrict__ xl, const float* __restrict__ logit,
    const float* __restrict__ bias, const int* __restrict__ rowptr,
    const int* __restrict__ adj, float* __restrict__ out, int n) {
  int wid = (blockIdx.x * blockDim.x + threadIdx.x) >> 6;
  int lane = threadIdx.x & 63;
  if (wid >= n) return;
  const bool act = lane < NCLS;
  const int beg = rowptr[wid], end = rowptr[wid + 1];

  // node max over precomputed logits (once per node)
  float mx = -1e30f;
  for (int i = beg + lane; i < end; i += 64) mx = fmaxf(mx, logit[i]);
  #pragma unroll
  for (int off = 1; off < 64; off <<= 1) mx = fmaxf(mx, __shfl_xor(mx, off, 64));

  float denom = 0.f, acc = 0.f;
  int i = beg;
  for (; i + 1 < end; i += 2) {
    int u0 = adj[i], u1 = adj[i + 1];
    float w0 = __expf(logit[i] - mx);
    float w1 = __expf(logit[i + 1] - mx);
    float x0 = act ? b2f(xl[(size_t)u0 * L2PAD + lane]) : 0.f;
    float x1 = act ? b2f(xl[(size_t)u1 * L2PAD + lane]) : 0.f;
    denom += w0 + w1;
    acc += w0 * x0 + w1 * x1;
  }
  if (i < end) {
    int u0 = adj[i];
    float w0 = __expf(logit[i] - mx);
    float x0 = act ? b2f(xl[(size_t)u0 * L2PAD + lane]) : 0.f;
    denom += w0;
    acc += w0 * x0;
  }

  float r = acc / (denom + 1e-16f) + (act ? bias[lane] : 0.f);
  float rm = act ? r : -1e30f;
  #pragma unroll
  for (int off = 1; off < 64; off <<= 1) rm = fmaxf(rm, __shfl_xor(rm, off, 64));
  float se = act ? __expf(r - rm) : 0.f;
  #pragma unroll
  for (int off = 1; off < 64; off <<= 1) se += __shfl_xor(se, off, 64);
  if (act) out[(size_t)wid * NCLS + lane] = r - rm - __logf(se);
}

// ---------------- launch ----------------
extern "C" void kernel_launch(void* const* d_in, const int* in_sizes, int n_in,
                              void* d_out, int out_size, void* d_ws, size_t ws_size,
                              hipStream_t stream) {
  const float* x   = (const float*)d_in[0];
  const int* ei    = (const int*)d_in[1];
  const float* Wl0 = (const float*)d_in[2];
  const float* Wr0 = (const float*)d_in[3];
  const float* a0  = (const float*)d_in[4];
  const float* b0  = (const float*)d_in[5];
  const float* Wl1 = (const float*)d_in[6];
  const float* Wr1 = (const float*)d_in[7];
  const float* a1  = (const float*)d_in[8];
  const float* b1  = (const float*)d_in[9];
  const float* Wl2 = (const float*)d_in[10];
  const float* Wr2 = (const float*)d_in[11];
  const float* a2  = (const float*)d_in[12];
  const float* b2  = (const float*)d_in[13];

  const int N = in_sizes[0] / NFEAT;   // 50000
  const int E = in_sizes[1] / 2;       // 800000
  const int* src = ei;
  const int* dst = ei + E;
  const int total = E + N;             // CSR slots incl. self-loops

  // workspace carve-up (~131 MB)
  char* ws = (char*)d_ws;
  unsigned short* xlb = (unsigned short*)ws; ws += (size_t)N * HID * 2;
  unsigned short* xrb = (unsigned short*)ws; ws += (size_t)N * HID * 2;
  unsigned short* xb  = (unsigned short*)ws; ws += (size_t)N * HID * 2;  // input bf16 / hidden
  unsigned short* hb  = (unsigned short*)ws; ws += (size_t)N * HID * 2;
  unsigned short* WT  = (unsigned short*)ws; ws += (size_t)6 * HID * HID * 2;
  float* logit = (float*)ws; ws += (size_t)total * sizeof(float);
  float* att48 = (float*)ws; ws += 64 * sizeof(float);
  int* deg    = (int*)ws; ws += (size_t)N * sizeof(int);
  int* rowptr = (int*)ws; ws += (size_t)(N + 8) * sizeof(int);
  int* bsum   = (int*)ws; ws += (size_t)64 * sizeof(int);
  int* adj    = (int*)ws; ws += (size_t)total * sizeof(int);
  int* vdst   = (int*)ws; ws += (size_t)total * sizeof(int);

  unsigned short* WlT0 = WT + 0 * HID * HID;
  unsigned short* WrT0 = WT + 1 * HID * HID;
  unsigned short* WlT1 = WT + 2 * HID * HID;
  unsigned short* WrT1 = WT + 3 * HID * HID;
  unsigned short* WlT2 = WT + 4 * HID * HID;
  unsigned short* WrT2 = WT + 5 * HID * HID;

  const int TB = 256;
  const int nbScan = (N + 1023) / 1024;

  // --- prep ---
  k_cast_bf16<<<(N * NFEAT / 4 + TB - 1) / TB, TB, 0, stream>>>(x, xb, N * NFEAT / 4);
  k_wt<<<(HID * NFEAT + TB - 1) / TB, TB, 0, stream>>>(Wl0, WlT0, NFEAT, HID, HID);
  k_wt<<<(HID * NFEAT + TB - 1) / TB, TB, 0, stream>>>(Wr0, WrT0, NFEAT, HID, HID);
  k_wt<<<(HID * HID + TB - 1) / TB, TB, 0, stream>>>(Wl1, WlT1, HID, HID, HID);
  k_wt<<<(HID * HID + TB - 1) / TB, TB, 0, stream>>>(Wr1, WrT1, HID, HID, HID);
  k_wt<<<(L2PAD * HID + TB - 1) / TB, TB, 0, stream>>>(Wl2, WlT2, HID, NCLS, L2PAD);
  k_wt<<<(L2PAD * HID + TB - 1) / TB, TB, 0, stream>>>(Wr2, WrT2, HID, NCLS, L2PAD);
  k_pad_att<<<1, 64, 0, stream>>>(a2, att48);

  // --- CSR build ---
  k_init_deg<<<(N + TB - 1) / TB, TB, 0, stream>>>(deg, N);
  k_count<<<(E + TB - 1) / TB, TB, 0, stream>>>(dst, deg, E);
  k_bsum<<<nbScan, TB, 0, stream>>>(deg, bsum, N);
  k_scanb<<<1, 64, 0, stream>>>(bsum, nbScan);
  k_scanfinal<<<nbScan, TB, 0, stream>>>(deg, bsum, rowptr, N);
  k_init_csr<<<(N + TB - 1) / TB, TB, 0, stream>>>(rowptr, adj, vdst, deg, N);
  k_scatter<<<(E + TB - 1) / TB, TB, 0, stream>>>(src, dst, deg, adj, vdst, E);

  const int nodeBlocks = (N + 3) / 4;
  const int rowBlocks = (N + 63) / 64;

  // --- layer 0 ---
  {
    dim3 g(rowBlocks, HID / 64);
    gemm_dual_bf16<<<g, 256, 0, stream>>>(xb, WlT0, WrT0, xlb, xrb, N, NFEAT, HID);
    gat_node_hc<<<nodeBlocks, 256, 0, stream>>>(xlb, xrb, a0, b0, rowptr, adj, hb, N);
  }
  // --- layer 1 ---
  {
    dim3 g(rowBlocks, HID / 64);
    gemm_dual_bf16<<<g, 256, 0, stream>>>(hb, WlT1, WrT1, xlb, xrb, N, HID, HID);
    gat_node_hc<<<nodeBlocks, 256, 0, stream>>>(xlb, xrb, a1, b1, rowptr, adj, xb, N);
  }
  // --- layer 2 ---
  {
    dim3 g(rowBlocks, 1);
    gemm_dual_bf16<<<g, 256, 0, stream>>>(xb, WlT2, WrT2, xlb, xrb, N, HID, L2PAD);
    k_logit_l2<<<(total + TB - 1) / TB, TB, 0, stream>>>(xlb, xrb, att48, adj,
                                                         vdst, logit, total);
    gat_node_l2<<<nodeBlocks, 256, 0, stream>>>(xlb, logit, b2, rowptr, adj,
                                                (float*)d_out, N);
  }
}

// Round 5
// 425.726 us; speedup vs baseline: 1.9781x; 1.0456x over previous
//
#include <hip/hip_runtime.h>
#include <cmath>

// GATv2 3-layer forward, round 4:
//  - hc: 4 edges/iteration (2 independent gathers in flight per half-wave)
//  - GEMM: global_load_lds(16B) staging, XOR-swizzled (pre-swizzled global
//    source + swizzled LDS reads, linear DMA dest), col-major grid for X reuse
//  - prep: 6 weight transposes fused into one launch

#define NFEAT 128
#define HID 256
#define NCLS 47
#define L2PAD 64

typedef __attribute__((ext_vector_type(8))) short bf16x8;
typedef __attribute__((ext_vector_type(4))) float f32x4;
typedef __attribute__((ext_vector_type(2))) float f32x2;

__device__ __forceinline__ unsigned short f2b(float f) {
  unsigned int u = __builtin_bit_cast(unsigned int, f);
  u += 0x7FFFu + ((u >> 16) & 1u);  // RNE
  return (unsigned short)(u >> 16);
}
__device__ __forceinline__ float b2f(unsigned short s) {
  return __builtin_bit_cast(float, (unsigned int)s << 16);
}
__device__ __forceinline__ f32x2 b2f2(unsigned int u) {
  return (f32x2){__builtin_bit_cast(float, u << 16),
                 __builtin_bit_cast(float, u & 0xFFFF0000u)};
}

__device__ __forceinline__ void glds16(const unsigned short* g, unsigned short* l) {
  __builtin_amdgcn_global_load_lds(
      (const __attribute__((address_space(1))) unsigned int*)g,
      (__attribute__((address_space(3))) unsigned int*)l, 16, 0, 0);
}

// ---------------- prep ----------------
__global__ void k_cast_bf16(const float* __restrict__ in,
                            unsigned short* __restrict__ out, int n4) {
  int i = blockIdx.x * blockDim.x + threadIdx.x;
  if (i < n4) {
    float4 v = reinterpret_cast<const float4*>(in)[i];
    ushort4 o = {f2b(v.x), f2b(v.y), f2b(v.z), f2b(v.w)};
    reinterpret_cast<ushort4*>(out)[i] = o;
  }
}

// all 6 weight transposes in one launch. W[s]: [K][M] f32 -> WT[s]: [Mpad][K] bf16
struct WtArgs {
  const float* W[6];
  unsigned short* WT[6];
  int K[6], M[6], off[6], total;
};
__global__ void k_wt_all(WtArgs a) {
  int i = blockIdx.x * blockDim.x + threadIdx.x;
  if (i >= a.total) return;
  int s = 0;
  #pragma unroll
  for (int j = 1; j < 6; ++j) if (i >= a.off[j]) s = j;
  int jj = i - a.off[s];
  int K = a.K[s], M = a.M[s];
  int m = jj / K, k = jj - m * K;
  a.WT[s][jj] = (m < M) ? f2b(a.W[s][(size_t)k * M + m]) : (unsigned short)0;
}

__global__ void k_pad_att(const float* __restrict__ a, float* __restrict__ out48) {
  int i = threadIdx.x;
  if (i < 48) out48[i] = (i < NCLS) ? a[i] : 0.f;
}

// ---------------- CSR build ----------------
__global__ void k_init_deg(int* __restrict__ deg, int n) {
  int i = blockIdx.x * blockDim.x + threadIdx.x;
  if (i < n) deg[i] = 1;  // self-loop
}

__global__ void k_count(const int* __restrict__ dst, int* __restrict__ deg, int e) {
  int i = blockIdx.x * blockDim.x + threadIdx.x;
  if (i < e) atomicAdd(&deg[dst[i]], 1);
}

__global__ __launch_bounds__(256) void k_bsum(const int* __restrict__ deg,
                                              int* __restrict__ bsum, int n) {
  int t = threadIdx.x;
  int base = blockIdx.x * 1024 + t * 4;
  int s = 0;
  if (base + 3 < n) {
    int4 v = *reinterpret_cast<const int4*>(deg + base);
    s = v.x + v.y + v.z + v.w;
  } else {
    for (int j = 0; j < 4; ++j) { int i = base + j; if (i < n) s += deg[i]; }
  }
  #pragma unroll
  for (int off = 1; off < 64; off <<= 1) s += __shfl_xor(s, off, 64);
  __shared__ int wsum[4];
  if ((t & 63) == 0) wsum[t >> 6] = s;
  __syncthreads();
  if (t == 0) bsum[blockIdx.x] = wsum[0] + wsum[1] + wsum[2] + wsum[3];
}

__global__ void k_scanb(int* __restrict__ bsum, int nb) {
  int lane = threadIdx.x;
  int v = (lane < nb) ? bsum[lane] : 0;
  #pragma unroll
  for (int off = 1; off < 64; off <<= 1) {
    int u = __shfl_up(v, off, 64);
    if (lane >= off) v += u;
  }
  if (lane < nb) bsum[lane] = v;
}

__global__ __launch_bounds__(256) void k_scanfinal(const int* __restrict__ deg,
                                                   const int* __restrict__ bscan,
                                                   int* __restrict__ rowptr, int n) {
  int t = threadIdx.x, b = blockIdx.x;
  int base = b * 1024 + t * 4;
  int v0 = 0, v1 = 0, v2 = 0, v3 = 0;
  if (base + 3 < n) {
    int4 v = *reinterpret_cast<const int4*>(deg + base);
    v0 = v.x; v1 = v.y; v2 = v.z; v3 = v.w;
  } else {
    if (base < n) v0 = deg[base];
    if (base + 1 < n) v1 = deg[base + 1];
    if (base + 2 < n) v2 = deg[base + 2];
    if (base + 3 < n) v3 = deg[base + 3];
  }
  int s = v0 + v1 + v2 + v3;
  int incl = s;
  #pragma unroll
  for (int off = 1; off < 64; off <<= 1) {
    int u = __shfl_up(incl, off, 64);
    if ((t & 63) >= off) incl += u;
  }
  __shared__ int wsum[4];
  int w = t >> 6, l = t & 63;
  if (l == 63) wsum[w] = incl;
  __syncthreads();
  int woff = 0;
  for (int j = 0; j < w; ++j) woff += wsum[j];
  int excl = incl - s + woff;
  int boff = (b == 0) ? 0 : bscan[b - 1];
  int p = boff + excl;
  if (base < n)     rowptr[base + 1] = p + v0;
  if (base + 1 < n) rowptr[base + 2] = p + v0 + v1;
  if (base + 2 < n) rowptr[base + 3] = p + v0 + v1 + v2;
  if (base + 3 < n) rowptr[base + 4] = p + v0 + v1 + v2 + v3;
  if (b == 0 && t == 0) rowptr[0] = 0;
}

__global__ void k_init_csr(const int* __restrict__ rowptr, int* __restrict__ adj,
                           int* __restrict__ vdst, int* __restrict__ cursor, int n) {
  int i = blockIdx.x * blockDim.x + threadIdx.x;
  if (i < n) { int p = rowptr[i]; adj[p] = i; vdst[p] = i; cursor[i] = p + 1; }
}

__global__ void k_scatter(const int* __restrict__ src, const int* __restrict__ dst,
                          int* __restrict__ cursor, int* __restrict__ adj,
                          int* __restrict__ vdst, int e) {
  int i = blockIdx.x * blockDim.x + threadIdx.x;
  if (i < e) {
    int d = dst[i];
    int p = atomicAdd(&cursor[d], 1);
    adj[p] = src[i];
    vdst[p] = d;
  }
}

// ---------------- dual bf16 MFMA GEMM (glds + XOR swizzle) ----------------
// X: [N][K] bf16, WlT/WrT: [Mpad][K] bf16, XL/XR: [N][Mpad] bf16.
// Tile 64x64, BK=64. LDS chunk c (16B) holds global chunk (c16 ^ (row&7)) of
// row c>>3 — DMA dest is linear, source pre-swizzled, reads swizzled.
__global__ __launch_bounds__(256) void gemm_dual_bf16(
    const unsigned short* __restrict__ X, const unsigned short* __restrict__ WlT,
    const unsigned short* __restrict__ WrT, unsigned short* __restrict__ XL,
    unsigned short* __restrict__ XR, int N, int K, int Mpad) {
  __shared__ __align__(16) unsigned short S[3 * 64 * 64];
  unsigned short* Xs = S;
  unsigned short* Ls = S + 4096;
  unsigned short* Rs = S + 8192;

  const int t = threadIdx.x;
  const int col0 = blockIdx.x * 64;   // x = col-block: consecutive blocks share X
  const int row0 = blockIdx.y * 64;
  const int w = t >> 6, lane = t & 63;
  const int r15 = lane & 15, kc = lane >> 4;
  const bool tail = (row0 + 64 > N);

  // staging chunk coords: pass0 chunk = t, pass1 chunk = t + 256
  const int rowa = t >> 3, c16a = t & 7;
  const int rowb = (t + 256) >> 3, c16b = t & 7;  // (t+256)&7 == t&7
  const int sga = (c16a ^ (rowa & 7)) * 8;        // swizzled k-offset (ushorts)
  const int sgb = (c16b ^ (rowb & 7)) * 8;
  unsigned short* ldst0 = S + (w * 512);          // wave-uniform DMA bases
  unsigned short* ldst1 = S + (2048 + w * 512);

  f32x4 accL[4], accR[4];
  #pragma unroll
  for (int i = 0; i < 4; ++i) {
    accL[i] = (f32x4){0.f, 0.f, 0.f, 0.f};
    accR[i] = (f32x4){0.f, 0.f, 0.f, 0.f};
  }

  const int rA = 16 * w + r15;

  for (int k0 = 0; k0 < K; k0 += 64) {
    // W staging (rows always valid: buffers padded to Mpad)
    glds16(WlT + (size_t)(col0 + rowa) * K + k0 + sga, ldst0 + 4096);
    glds16(WlT + (size_t)(col0 + rowb) * K + k0 + sgb, ldst1 + 4096);
    glds16(WrT + (size_t)(col0 + rowa) * K + k0 + sga, ldst0 + 8192);
    glds16(WrT + (size_t)(col0 + rowb) * K + k0 + sgb, ldst1 + 8192);
    if (!tail) {
      glds16(X + (size_t)(row0 + rowa) * K + k0 + sga, ldst0);
      glds16(X + (size_t)(row0 + rowb) * K + k0 + sgb, ldst1);
    } else {
      uint4 va = (uint4){0, 0, 0, 0}, vb = (uint4){0, 0, 0, 0};
      if (row0 + rowa < N)
        va = *reinterpret_cast<const uint4*>(X + (size_t)(row0 + rowa) * K + k0 + sga);
      if (row0 + rowb < N)
        vb = *reinterpret_cast<const uint4*>(X + (size_t)(row0 + rowb) * K + k0 + sgb);
      *reinterpret_cast<uint4*>(Xs + rowa * 64 + c16a * 8) = va;
      *reinterpret_cast<uint4*>(Xs + rowb * 64 + c16b * 8) = vb;
    }
    __syncthreads();

    #pragma unroll
    for (int ks = 0; ks < 2; ++ks) {
      const int c16 = ks * 4 + kc;
      const bf16x8 a = *reinterpret_cast<const bf16x8*>(
          Xs + rA * 64 + ((c16 ^ (rA & 7)) * 8));
      #pragma unroll
      for (int nf = 0; nf < 4; ++nf) {
        const int rB = nf * 16 + r15;
        const int so = rB * 64 + ((c16 ^ (rB & 7)) * 8);
        const bf16x8 bl = *reinterpret_cast<const bf16x8*>(Ls + so);
        const bf16x8 br = *reinterpret_cast<const bf16x8*>(Rs + so);
        accL[nf] = __builtin_amdgcn_mfma_f32_16x16x32_bf16(a, bl, accL[nf], 0, 0, 0);
        accR[nf] = __builtin_amdgcn_mfma_f32_16x16x32_bf16(a, br, accR[nf], 0, 0, 0);
      }
    }
    __syncthreads();
  }

  // C/D layout: col=lane&15, row=(lane>>4)*4+reg
  #pragma unroll
  for (int nf = 0; nf < 4; ++nf) {
    int cc = col0 + nf * 16 + r15;
    #pragma unroll
    for (int i = 0; i < 4; ++i) {
      int rr = row0 + 16 * w + kc * 4 + i;
      if (rr < N) {
        XL[(size_t)rr * Mpad + cc] = f2b(accL[nf][i]);
        XR[(size_t)rr * Mpad + cc] = f2b(accR[nf][i]);
      }
    }
  }
}

// ---------------- fused node kernel, layers 0/1 (H=8, C=32) ----------------
// 1 wave/node; half-wave per edge, 4 edges per iteration (2 loads in flight
// per half). Slot q holds values [8q,8q+8); head = q>>2; reduce = 2 shfls.
__global__ __launch_bounds__(256) void gat_node_hc(
    const unsigned short* __restrict__ xl, const unsigned short* __restrict__ xr,
    const float* __restrict__ att, const float* __restrict__ bias,
    const int* __restrict__ rowptr, const int* __restrict__ adj,
    unsigned short* __restrict__ out, int n) {
  int wid = (blockIdx.x * blockDim.x + threadIdx.x) >> 6;
  int lane = threadIdx.x & 63;
  if (wid >= n) return;
  const int q = lane & 31, half = lane >> 5;

  const uint4 xrp = *reinterpret_cast<const uint4*>(xr + (size_t)wid * HID + q * 8);
  const f32x2 xr2[4] = {b2f2(xrp.x), b2f2(xrp.y), b2f2(xrp.z), b2f2(xrp.w)};
  const float4 af0 = *reinterpret_cast<const float4*>(att + q * 8);
  const float4 af1 = *reinterpret_cast<const float4*>(att + q * 8 + 4);
  const f32x2 a2[4] = {{af0.x, af0.y}, {af0.z, af0.w},
                       {af1.x, af1.y}, {af1.z, af1.w}};

  float m = -1e30f, denom = 0.f;
  f32x2 acc[4] = {{0.f, 0.f}, {0.f, 0.f}, {0.f, 0.f}, {0.f, 0.f}};

  const int beg = rowptr[wid], end = rowptr[wid + 1];
  for (int base = beg; base < end; base += 4) {
    const int e0 = base + half, e1 = base + 2 + half;
    const bool act0 = e0 < end, act1 = e1 < end;
    const int u0 = adj[act0 ? e0 : beg];
    const int u1 = adj[act1 ? e1 : beg];
    // two independent gathers in flight
    const uint4 p0 = *reinterpret_cast<const uint4*>(xl + (size_t)u0 * HID + q * 8);
    const uint4 p1 = *reinterpret_cast<const uint4*>(xl + (size_t)u1 * HID + q * 8);
    const f32x2 x0[4] = {b2f2(p0.x), b2f2(p0.y), b2f2(p0.z), b2f2(p0.w)};
    const f32x2 x1[4] = {b2f2(p1.x), b2f2(p1.y), b2f2(p1.z), b2f2(p1.w)};
    float part0, part1;
    {
      f32x2 s2 = {0.f, 0.f};
      #pragma unroll
      for (int j = 0; j < 4; ++j) {
        f32x2 z = x0[j] + xr2[j];
        f32x2 lz = 0.2f * z;
        f32x2 r = {fmaxf(z.x, lz.x), fmaxf(z.y, lz.y)};
        s2 += r * a2[j];
      }
      part0 = s2.x + s2.y;
      part0 += __shfl_xor(part0, 1, 64);
      part0 += __shfl_xor(part0, 2, 64);
      if (!act0) part0 = -1e30f;
    }
    {
      f32x2 s2 = {0.f, 0.f};
      #pragma unroll
      for (int j = 0; j < 4; ++j) {
        f32x2 z = x1[j] + xr2[j];
        f32x2 lz = 0.2f * z;
        f32x2 r = {fmaxf(z.x, lz.x), fmaxf(z.y, lz.y)};
        s2 += r * a2[j];
      }
      part1 = s2.x + s2.y;
      part1 += __shfl_xor(part1, 1, 64);
      part1 += __shfl_xor(part1, 2, 64);
      if (!act1) part1 = -1e30f;
    }
    if (__any(fmaxf(part0, part1) > m + 8.f)) {
      {
        float mn = fmaxf(m, part0);
        float so = __expf(m - mn);
        float wn = act0 ? __expf(part0 - mn) : 0.f;
        denom = denom * so + wn;
        #pragma unroll
        for (int j = 0; j < 4; ++j) acc[j] = acc[j] * so + wn * x0[j];
        m = mn;
      }
      {
        float mn = fmaxf(m, part1);
        float so = __expf(m - mn);
        float wn = act1 ? __expf(part1 - mn) : 0.f;
        denom = denom * so + wn;
        #pragma unroll
        for (int j = 0; j < 4; ++j) acc[j] = acc[j] * so + wn * x1[j];
        m = mn;
      }
    } else {
      float w0 = act0 ? __expf(part0 - m) : 0.f;
      float w1 = act1 ? __expf(part1 - m) : 0.f;
      denom += w0 + w1;
      #pragma unroll
      for (int j = 0; j < 4; ++j) acc[j] += w0 * x0[j] + w1 * x1[j];
    }
  }

  // merge the two half-wave softmax states
  float mo = __shfl_xor(m, 32, 64);
  float ms = fmaxf(m, mo);
  float sc = __expf(m - ms);
  denom *= sc;
  denom += __shfl_xor(denom, 32, 64);
  #pragma unroll
  for (int j = 0; j < 4; ++j) {
    acc[j] *= sc;
    acc[j].x += __shfl_xor(acc[j].x, 32, 64);
    acc[j].y += __shfl_xor(acc[j].y, 32, 64);
  }

  if (half == 0) {
    const float inv = 1.f / (denom + 1e-16f);
    const float4 bf0 = *reinterpret_cast<const float4*>(bias + q * 8);
    const float4 bf1 = *reinterpret_cast<const float4*>(bias + q * 8 + 4);
    float o[8] = {acc[0].x * inv + bf0.x, acc[0].y * inv + bf0.y,
                  acc[1].x * inv + bf0.z, acc[1].y * inv + bf0.w,
                  acc[2].x * inv + bf1.x, acc[2].y * inv + bf1.y,
                  acc[3].x * inv + bf1.z, acc[3].y * inv + bf1.w};
    #pragma unroll
    for (int j = 0; j < 8; ++j) o[j] = o[j] > 0.f ? o[j] : (__expf(o[j]) - 1.f);
    uint4 ov;
    ov.x = (unsigned)f2b(o[0]) | ((unsigned)f2b(o[1]) << 16);
    ov.y = (unsigned)f2b(o[2]) | ((unsigned)f2b(o[3]) << 16);
    ov.z = (unsigned)f2b(o[4]) | ((unsigned)f2b(o[5]) << 16);
    ov.w = (unsigned)f2b(o[6]) | ((unsigned)f2b(o[7]) << 16);
    *reinterpret_cast<uint4*>(out + (size_t)wid * HID + q * 8) = ov;
  }
}

// ---------------- layer-2 edge logits (lane = CSR slot) ----------------
__global__ __launch_bounds__(256) void k_logit_l2(
    const unsigned short* __restrict__ xl, const unsigned short* __restrict__ xr,
    const float* __restrict__ att48, const int* __restrict__ adj,
    const int* __restrict__ vdst, float* __restrict__ logit, int total) {
  int i = blockIdx.x * blockDim.x + threadIdx.x;
  if (i >= total) return;
  const int u = adj[i], v = vdst[i];
  const uint4* pu = reinterpret_cast<const uint4*>(xl + (size_t)u * L2PAD);
  const uint4* pv = reinterpret_cast<const uint4*>(xr + (size_t)v * L2PAD);
  f32x2 s2 = {0.f, 0.f};
  #pragma unroll
  for (int b = 0; b < 6; ++b) {  // 6 x 8 = 48 values (47 real + 1 zero pad)
    const uint4 xu = pu[b], xv = pv[b];
    const f32x2* a2 = reinterpret_cast<const f32x2*>(att48 + b * 8);
    const unsigned ua[4] = {xu.x, xu.y, xu.z, xu.w};
    const unsigned va[4] = {xv.x, xv.y, xv.z, xv.w};
    #pragma unroll
    for (int j = 0; j < 4; ++j) {
      f32x2 z = b2f2(ua[j]) + b2f2(va[j]);
      f32x2 lz = 0.2f * z;
      f32x2 r = {fmaxf(z.x, lz.x), fmaxf(z.y, lz.y)};
      s2 += r * a2[j];
    }
  }
  logit[i] = s2.x + s2.y;
}

// ---------------- layer-2 aggregation + log_softmax ----------------
__global__ __launch_bounds__(256) void gat_node_l2(
    const unsigned short* __restrict__ xl, const float* __restrict__ logit,
    const float* __restrict__ bias, const int* __restrict__ rowptr,
    const int* __restrict__ adj, float* __restrict__ out, int n) {
  int wid = (blockIdx.x * blockDim.x + threadIdx.x) >> 6;
  int lane = threadIdx.x & 63;
  if (wid >= n) return;
  const bool act = lane < NCLS;
  const int beg = rowptr[wid], end = rowptr[wid + 1];

  float mx = -1e30f;
  for (int i = beg + lane; i < end; i += 64) mx = fmaxf(mx, logit[i]);
  #pragma unroll
  for (int off = 1; off < 64; off <<= 1) mx = fmaxf(mx, __shfl_xor(mx, off, 64));

  float denom = 0.f, acc = 0.f;
  int i = beg;
  for (; i + 1 < end; i += 2) {
    int u0 = adj[i], u1 = adj[i + 1];
    float w0 = __expf(logit[i] - mx);
    float w1 = __expf(logit[i + 1] - mx);
    float x0 = act ? b2f(xl[(size_t)u0 * L2PAD + lane]) : 0.f;
    float x1 = act ? b2f(xl[(size_t)u1 * L2PAD + lane]) : 0.f;
    denom += w0 + w1;
    acc += w0 * x0 + w1 * x1;
  }
  if (i < end) {
    int u0 = adj[i];
    float w0 = __expf(logit[i] - mx);
    float x0 = act ? b2f(xl[(size_t)u0 * L2PAD + lane]) : 0.f;
    denom += w0;
    acc += w0 * x0;
  }

  float r = acc / (denom + 1e-16f) + (act ? bias[lane] : 0.f);
  float rm = act ? r : -1e30f;
  #pragma unroll
  for (int off = 1; off < 64; off <<= 1) rm = fmaxf(rm, __shfl_xor(rm, off, 64));
  float se = act ? __expf(r - rm) : 0.f;
  #pragma unroll
  for (int off = 1; off < 64; off <<= 1) se += __shfl_xor(se, off, 64);
  if (act) out[(size_t)wid * NCLS + lane] = r - rm - __logf(se);
}

// ---------------- launch ----------------
extern "C" void kernel_launch(void* const* d_in, const int* in_sizes, int n_in,
                              void* d_out, int out_size, void* d_ws, size_t ws_size,
                              hipStream_t stream) {
  const float* x   = (const float*)d_in[0];
  const int* ei    = (const int*)d_in[1];
  const float* Wl0 = (const float*)d_in[2];
  const float* Wr0 = (const float*)d_in[3];
  const float* a0  = (const float*)d_in[4];
  const float* b0  = (const float*)d_in[5];
  const float* Wl1 = (const float*)d_in[6];
  const float* Wr1 = (const float*)d_in[7];
  const float* a1  = (const float*)d_in[8];
  const float* b1  = (const float*)d_in[9];
  const float* Wl2 = (const float*)d_in[10];
  const float* Wr2 = (const float*)d_in[11];
  const float* a2  = (const float*)d_in[12];
  const float* b2  = (const float*)d_in[13];

  const int N = in_sizes[0] / NFEAT;   // 50000
  const int E = in_sizes[1] / 2;       // 800000
  const int* src = ei;
  const int* dst = ei + E;
  const int total = E + N;             // CSR slots incl. self-loops

  // workspace carve-up
  char* ws = (char*)d_ws;
  unsigned short* xlb = (unsigned short*)ws; ws += (size_t)N * HID * 2;
  unsigned short* xrb = (unsigned short*)ws; ws += (size_t)N * HID * 2;
  unsigned short* xb  = (unsigned short*)ws; ws += (size_t)N * HID * 2;
  unsigned short* hb  = (unsigned short*)ws; ws += (size_t)N * HID * 2;
  unsigned short* WT  = (unsigned short*)ws; ws += (size_t)6 * HID * HID * 2;
  float* logit = (float*)ws; ws += (size_t)total * sizeof(float);
  float* att48 = (float*)ws; ws += 64 * sizeof(float);
  int* deg    = (int*)ws; ws += (size_t)N * sizeof(int);
  int* rowptr = (int*)ws; ws += (size_t)(N + 8) * sizeof(int);
  int* bsum   = (int*)ws; ws += (size_t)64 * sizeof(int);
  int* adj    = (int*)ws; ws += (size_t)total * sizeof(int);
  int* vdst   = (int*)ws; ws += (size_t)total * sizeof(int);

  unsigned short* WlT0 = WT + 0 * HID * HID;
  unsigned short* WrT0 = WT + 1 * HID * HID;
  unsigned short* WlT1 = WT + 2 * HID * HID;
  unsigned short* WrT1 = WT + 3 * HID * HID;
  unsigned short* WlT2 = WT + 4 * HID * HID;
  unsigned short* WrT2 = WT + 5 * HID * HID;

  const int TB = 256;
  const int nbScan = (N + 1023) / 1024;

  // --- prep ---
  k_cast_bf16<<<(N * NFEAT / 4 + TB - 1) / TB, TB, 0, stream>>>(x, xb, N * NFEAT / 4);
  {
    WtArgs a;
    const float* Wsrc[6] = {Wl0, Wr0, Wl1, Wr1, Wl2, Wr2};
    unsigned short* Wdst[6] = {WlT0, WrT0, WlT1, WrT1, WlT2, WrT2};
    int Ks[6] = {NFEAT, NFEAT, HID, HID, HID, HID};
    int Ms[6] = {HID, HID, HID, HID, NCLS, NCLS};
    int Mp[6] = {HID, HID, HID, HID, L2PAD, L2PAD};
    int off = 0;
    for (int s = 0; s < 6; ++s) {
      a.W[s] = Wsrc[s]; a.WT[s] = Wdst[s]; a.K[s] = Ks[s]; a.M[s] = Ms[s];
      a.off[s] = off; off += Mp[s] * Ks[s];
    }
    a.total = off;
    k_wt_all<<<(a.total + TB - 1) / TB, TB, 0, stream>>>(a);
  }
  k_pad_att<<<1, 64, 0, stream>>>(a2, att48);

  // --- CSR build ---
  k_init_deg<<<(N + TB - 1) / TB, TB, 0, stream>>>(deg, N);
  k_count<<<(E + TB - 1) / TB, TB, 0, stream>>>(dst, deg, E);
  k_bsum<<<nbScan, TB, 0, stream>>>(deg, bsum, N);
  k_scanb<<<1, 64, 0, stream>>>(bsum, nbScan);
  k_scanfinal<<<nbScan, TB, 0, stream>>>(deg, bsum, rowptr, N);
  k_init_csr<<<(N + TB - 1) / TB, TB, 0, stream>>>(rowptr, adj, vdst, deg, N);
  k_scatter<<<(E + TB - 1) / TB, TB, 0, stream>>>(src, dst, deg, adj, vdst, E);

  const int nodeBlocks = (N + 3) / 4;
  const int rowBlocks = (N + 63) / 64;

  // --- layer 0 ---
  {
    dim3 g(HID / 64, rowBlocks);
    gemm_dual_bf16<<<g, 256, 0, stream>>>(xb, WlT0, WrT0, xlb, xrb, N, NFEAT, HID);
    gat_node_hc<<<nodeBlocks, 256, 0, stream>>>(xlb, xrb, a0, b0, rowptr, adj, hb, N);
  }
  // --- layer 1 ---
  {
    dim3 g(HID / 64, rowBlocks);
    gemm_dual_bf16<<<g, 256, 0, stream>>>(hb, WlT1, WrT1, xlb, xrb, N, HID, HID);
    gat_node_hc<<<nodeBlocks, 256, 0, stream>>>(xlb, xrb, a1, b1, rowptr, adj, xb, N);
  }
  // --- layer 2 ---
  {
    dim3 g(1, rowBlocks);
    gemm_dual_bf16<<<g, 256, 0, stream>>>(xb, WlT2, WrT2, xlb, xrb, N, HID, L2PAD);
    k_logit_l2<<<(total + TB - 1) / TB, TB, 0, stream>>>(xlb, xrb, att48, adj,
                                                         vdst, logit, total);
    gat_node_l2<<<nodeBlocks, 256, 0, stream>>>(xlb, logit, b2, rowptr, adj,
                                                (float*)d_out, N);
  }
}